// Round 1
// baseline (23268.300 us; speedup 1.0000x reference)
//
#include <hip/hip_runtime.h>

#define LN_EPS 1e-5f

// ---------------- degree / normalization ----------------

__global__ __launch_bounds__(256) void fill_deg(float* __restrict__ deg, int n) {
    int i = blockIdx.x * 256 + threadIdx.x;
    if (i < n) deg[i] = 1.0f;  // self-loop weight
}

__global__ __launch_bounds__(256) void deg_edges(const int* __restrict__ ei,
                                                 const float* __restrict__ w,
                                                 float* __restrict__ deg, int E) {
    int e = blockIdx.x * 256 + threadIdx.x;
    if (e < E) atomicAdd(&deg[ei[E + e]], w[e]);  // segment_sum over targets (col)
}

__global__ __launch_bounds__(256) void deg_to_dis(float* __restrict__ deg, int n) {
    int i = blockIdx.x * 256 + threadIdx.x;
    if (i < n) {
        float d = deg[i];
        deg[i] = d > 0.f ? rsqrtf(fmaxf(d, 1e-30f)) : 0.f;
    }
}

// ---------------- h = x @ W  (f32, vector ALU) ----------------
// 64-row x 64-col block tile; x staged transposed (k-major) + W staged, 64 KiB LDS total.
// 4x4 micro-tile per thread, 16 FMA per k.

__global__ __launch_bounds__(256) void gemm_xw(const float* __restrict__ x,
                                               const float* __restrict__ W,
                                               float* __restrict__ h, int n) {
    __shared__ float xt[128][64];  // xt[k][r] = x[brow+r][k]
    __shared__ float Ws[128][64];  // Ws[k][c] = W[k][chalf*64+c]
    const int tid = threadIdx.x;
    const int brow = blockIdx.x * 64;
    const int chalf = blockIdx.y;  // 0 or 1 (64 cols each)

    // stage x tile (transposed): 2048 float4 loads / 256 threads = 8 each
    for (int i = tid; i < 64 * 32; i += 256) {
        int r = i >> 5, c4 = i & 31, k0 = c4 * 4;
        int gr = brow + r;
        float4 v = make_float4(0.f, 0.f, 0.f, 0.f);
        if (gr < n) v = *(const float4*)(x + (size_t)gr * 128 + k0);
        xt[k0 + 0][r] = v.x; xt[k0 + 1][r] = v.y;
        xt[k0 + 2][r] = v.z; xt[k0 + 3][r] = v.w;
    }
    // stage W half: 128 rows x 16 float4
    for (int i = tid; i < 128 * 16; i += 256) {
        int k = i >> 4, c4 = i & 15;
        float4 v = *(const float4*)(W + (size_t)k * 128 + chalf * 64 + c4 * 4);
        *(float4*)&Ws[k][c4 * 4] = v;
    }
    __syncthreads();

    const int r0 = (tid >> 4) * 4;  // 16 row-groups
    const int c0 = (tid & 15) * 4;  // 16 col-groups
    float4 acc0 = make_float4(0, 0, 0, 0), acc1 = acc0, acc2 = acc0, acc3 = acc0;
    #pragma unroll 8
    for (int k = 0; k < 128; k++) {
        float4 xa = *(const float4*)&xt[k][r0];
        float4 wb = *(const float4*)&Ws[k][c0];
        acc0.x += xa.x * wb.x; acc0.y += xa.x * wb.y; acc0.z += xa.x * wb.z; acc0.w += xa.x * wb.w;
        acc1.x += xa.y * wb.x; acc1.y += xa.y * wb.y; acc1.z += xa.y * wb.z; acc1.w += xa.y * wb.w;
        acc2.x += xa.z * wb.x; acc2.y += xa.z * wb.y; acc2.z += xa.z * wb.z; acc2.w += xa.z * wb.w;
        acc3.x += xa.w * wb.x; acc3.y += xa.w * wb.y; acc3.z += xa.w * wb.z; acc3.w += xa.w * wb.w;
    }
    float4 accs[4] = {acc0, acc1, acc2, acc3};
    #pragma unroll
    for (int i = 0; i < 4; i++) {
        int gr = brow + r0 + i;
        if (gr < n) *(float4*)(h + (size_t)gr * 128 + chalf * 64 + c0) = accs[i];
    }
}

// ---------------- edge scatter: out[col] += norm * h[row] ----------------
// 8 lanes per edge, 16 features (4 float4) per lane, atomics into d_out.

__global__ __launch_bounds__(256) void scatter_edges(const int* __restrict__ ei,
                                                     const float* __restrict__ w,
                                                     const float* __restrict__ dis,
                                                     const float* __restrict__ h,
                                                     float* __restrict__ out, int E) {
    long long item = (long long)blockIdx.x * 256 + threadIdx.x;
    long long total = (long long)E * 8;
    if (item >= total) return;
    long long e = item >> 3;
    int f0 = (int)(item & 7) * 16;
    int r = ei[e], c = ei[(long long)E + e];
    float nrm = dis[r] * w[e] * dis[c];
    const float4* hp = (const float4*)(h + (size_t)r * 128 + f0);
    float* op = out + (size_t)c * 128 + f0;
    #pragma unroll
    for (int j = 0; j < 4; j++) {
        float4 v = hp[j];
        atomicAdd(op + 4 * j + 0, nrm * v.x);
        atomicAdd(op + 4 * j + 1, nrm * v.y);
        atomicAdd(op + 4 * j + 2, nrm * v.z);
        atomicAdd(op + 4 * j + 3, nrm * v.w);
    }
}

// ---------------- self-loop + bias + LayerNorm + ReLU ----------------
// one wave per node; lane l owns features 2l, 2l+1.

__global__ __launch_bounds__(256) void ln_relu(const float* __restrict__ h,
                                               const float* __restrict__ dis,
                                               const float* __restrict__ b,
                                               const float* __restrict__ gamma,
                                               const float* __restrict__ beta,
                                               float* __restrict__ out, int n) {
    int wave = threadIdx.x >> 6;
    int lane = threadIdx.x & 63;
    int node = blockIdx.x * 4 + wave;
    if (node >= n) return;
    float ds = dis[node];
    float sw = ds * ds;  // self-loop norm: dis[i]*1*dis[i]
    const float2* ap = (const float2*)(out + (size_t)node * 128);
    const float2* hp = (const float2*)(h + (size_t)node * 128);
    float2 a = ap[lane], hh = hp[lane];
    float2 bb = ((const float2*)b)[lane];
    float vx = a.x + sw * hh.x + bb.x;
    float vy = a.y + sw * hh.y + bb.y;
    float s = vx + vy;
    #pragma unroll
    for (int off = 32; off; off >>= 1) s += __shfl_xor(s, off);
    float mu = s * (1.0f / 128.0f);
    float dx = vx - mu, dy = vy - mu;
    float q = dx * dx + dy * dy;
    #pragma unroll
    for (int off = 32; off; off >>= 1) q += __shfl_xor(q, off);
    float rs = rsqrtf(q * (1.0f / 128.0f) + LN_EPS);
    float2 g = ((const float2*)gamma)[lane], be = ((const float2*)beta)[lane];
    float2 o;
    o.x = fmaxf(dx * rs * g.x + be.x, 0.f);
    o.y = fmaxf(dy * rs * g.y + be.y, 0.f);
    ((float2*)(out + (size_t)node * 128))[lane] = o;
}

// ---------------- launcher ----------------

extern "C" void kernel_launch(void* const* d_in, const int* in_sizes, int n_in,
                              void* d_out, int out_size, void* d_ws, size_t ws_size,
                              hipStream_t stream) {
    const float* x     = (const float*)d_in[0];
    const int*   ei    = (const int*)d_in[1];   // [2, E] int32
    const float* ew    = (const float*)d_in[2];
    const float* W     = (const float*)d_in[3];
    const float* b     = (const float*)d_in[4];
    const float* gamma = (const float*)d_in[5];
    const float* beta  = (const float*)d_in[6];

    const int n = in_sizes[0] / 128;
    const int E = in_sizes[2];

    float* out = (float*)d_out;
    // workspace layout: [deg/dis: n floats][pad to 512KB][h: n*128 floats]
    float* deg = (float*)d_ws;
    float* h   = (float*)((char*)d_ws + 512 * 1024);

    // zero the aggregation target (harness poisons d_out with 0xAA)
    hipMemsetAsync(d_out, 0, (size_t)n * 128 * sizeof(float), stream);

    fill_deg<<<(n + 255) / 256, 256, 0, stream>>>(deg, n);
    deg_edges<<<(E + 255) / 256, 256, 0, stream>>>(ei, ew, deg, E);
    deg_to_dis<<<(n + 255) / 256, 256, 0, stream>>>(deg, n);

    dim3 ggrid((n + 63) / 64, 2);
    gemm_xw<<<ggrid, 256, 0, stream>>>(x, W, h, n);

    long long items = (long long)E * 8;
    int sblocks = (int)((items + 255) / 256);
    scatter_edges<<<sblocks, 256, 0, stream>>>(ei, ew, deg, h, out, E);

    ln_relu<<<(n + 3) / 4, 256, 0, stream>>>(h, deg, b, gamma, beta, out, n);
}

// Round 4
// 1199.098 us; speedup vs baseline: 19.4048x; 19.4048x over previous
//
#include <hip/hip_runtime.h>

#define LN_EPS 1e-5f

// ---------------- degree + in-degree histogram ----------------

__global__ __launch_bounds__(256) void fill_deg(float* __restrict__ deg, int n) {
    int i = blockIdx.x * 256 + threadIdx.x;
    if (i < n) deg[i] = 1.0f;  // self-loop weight
}

__global__ __launch_bounds__(256) void hist_edges(const int* __restrict__ ei,
                                                  const float* __restrict__ w,
                                                  float* __restrict__ deg,
                                                  int* __restrict__ counts, int E) {
    int e = blockIdx.x * 256 + threadIdx.x;
    if (e < E) {
        int c = ei[(long long)E + e];
        atomicAdd(&deg[c], w[e]);   // weighted degree (normalization)
        atomicAdd(&counts[c], 1);   // unweighted in-degree (CSR)
    }
}

__global__ __launch_bounds__(256) void deg_to_dis(float* __restrict__ deg, int n) {
    int i = blockIdx.x * 256 + threadIdx.x;
    if (i < n) {
        float d = deg[i];
        deg[i] = d > 0.f ? rsqrtf(fmaxf(d, 1e-30f)) : 0.f;
    }
}

// ---------------- exclusive scan of counts -> row_ptr (single block) ----------------

__global__ __launch_bounds__(256) void scan_counts(const int* __restrict__ counts,
                                                   int* __restrict__ rp, int n, int E) {
    __shared__ int wsum[4];
    __shared__ int carry_s;
    if (threadIdx.x == 0) carry_s = 0;
    __syncthreads();
    const int lane = threadIdx.x & 63, wv = threadIdx.x >> 6;
    for (int base = 0; base < n; base += 256) {
        int i = base + (int)threadIdx.x;
        int v = (i < n) ? counts[i] : 0;
        int incl = v;
        #pragma unroll
        for (int off = 1; off < 64; off <<= 1) {
            int t = __shfl_up(incl, off);
            if (lane >= off) incl += t;
        }
        if (lane == 63) wsum[wv] = incl;
        __syncthreads();
        int woff = 0;
        for (int k = 0; k < wv; k++) woff += wsum[k];
        int carry = carry_s;
        if (i < n) rp[i] = carry + woff + incl - v;  // exclusive prefix
        __syncthreads();
        if (threadIdx.x == 255) carry_s = carry + woff + incl;
        __syncthreads();
    }
    if (threadIdx.x == 0) rp[n] = E;
}

// ---------------- counting-sort edges by target ----------------

__global__ __launch_bounds__(256) void sort_edges(const int* __restrict__ ei,
                                                  const float* __restrict__ w,
                                                  const float* __restrict__ dis,
                                                  const int* __restrict__ rp,
                                                  int* __restrict__ cursor,
                                                  int* __restrict__ srcs,
                                                  float* __restrict__ coef, int E) {
    int e = blockIdx.x * 256 + threadIdx.x;
    if (e >= E) return;
    int r = ei[e], c = ei[(long long)E + e];
    int pos = rp[c] + atomicAdd(&cursor[c], 1);
    srcs[pos] = r;
    coef[pos] = dis[r] * w[e];  // dis[col] factored out, applied in agg_ln
}

// ---------------- h = x @ W  (f32, vector ALU) ----------------

__global__ __launch_bounds__(256) void gemm_xw(const float* __restrict__ x,
                                               const float* __restrict__ W,
                                               float* __restrict__ h, int n) {
    __shared__ float xt[128][64];  // xt[k][r] = x[brow+r][k]
    __shared__ float Ws[128][64];  // Ws[k][c] = W[k][chalf*64+c]
    const int tid = threadIdx.x;
    const int brow = blockIdx.x * 64;
    const int chalf = blockIdx.y;

    for (int i = tid; i < 64 * 32; i += 256) {
        int r = i >> 5, c4 = i & 31, k0 = c4 * 4;
        int gr = brow + r;
        float4 v = make_float4(0.f, 0.f, 0.f, 0.f);
        if (gr < n) v = *(const float4*)(x + (size_t)gr * 128 + k0);
        xt[k0 + 0][r] = v.x; xt[k0 + 1][r] = v.y;
        xt[k0 + 2][r] = v.z; xt[k0 + 3][r] = v.w;
    }
    for (int i = tid; i < 128 * 16; i += 256) {
        int k = i >> 4, c4 = i & 15;
        float4 v = *(const float4*)(W + (size_t)k * 128 + chalf * 64 + c4 * 4);
        *(float4*)&Ws[k][c4 * 4] = v;
    }
    __syncthreads();

    const int r0 = (tid >> 4) * 4;
    const int c0 = (tid & 15) * 4;
    float4 acc0 = make_float4(0, 0, 0, 0), acc1 = acc0, acc2 = acc0, acc3 = acc0;
    #pragma unroll 8
    for (int k = 0; k < 128; k++) {
        float4 xa = *(const float4*)&xt[k][r0];
        float4 wb = *(const float4*)&Ws[k][c0];
        acc0.x += xa.x * wb.x; acc0.y += xa.x * wb.y; acc0.z += xa.x * wb.z; acc0.w += xa.x * wb.w;
        acc1.x += xa.y * wb.x; acc1.y += xa.y * wb.y; acc1.z += xa.y * wb.z; acc1.w += xa.y * wb.w;
        acc2.x += xa.z * wb.x; acc2.y += xa.z * wb.y; acc2.z += xa.z * wb.z; acc2.w += xa.z * wb.w;
        acc3.x += xa.w * wb.x; acc3.y += xa.w * wb.y; acc3.z += xa.w * wb.z; acc3.w += xa.w * wb.w;
    }
    float4 accs[4] = {acc0, acc1, acc2, acc3};
    #pragma unroll
    for (int i = 0; i < 4; i++) {
        int gr = brow + r0 + i;
        if (gr < n) *(float4*)(h + (size_t)gr * 128 + chalf * 64 + c0) = accs[i];
    }
}

// ---------------- CSR gather-aggregate + self-loop + bias + LN + ReLU ----------------
// one wave per node; lane l owns features 2l, 2l+1; acc in registers, no atomics.

__global__ __launch_bounds__(256) void agg_ln(const int* __restrict__ rp,
                                              const int* __restrict__ srcs,
                                              const float* __restrict__ coef,
                                              const float* __restrict__ h,
                                              const float* __restrict__ dis,
                                              const float* __restrict__ b,
                                              const float* __restrict__ gamma,
                                              const float* __restrict__ beta,
                                              float* __restrict__ out, int n) {
    const int wave = threadIdx.x >> 6;
    const int lane = threadIdx.x & 63;
    const int node = blockIdx.x * 4 + wave;
    if (node >= n) return;

    const int j0 = rp[node], j1 = rp[node + 1];
    const float ds = dis[node];
    const float2* __restrict__ h2 = (const float2*)h;

    // self-loop term: dis[i] * h[i]  (outer dis[i] applied at the end)
    float2 hs = h2[(size_t)node * 64 + lane];
    float ax = ds * hs.x, ay = ds * hs.y;

    int j = j0;
    for (; j + 1 < j1; j += 2) {  // 2-edge unroll for ILP
        int s0 = srcs[j], s1 = srcs[j + 1];
        float c0 = coef[j], c1 = coef[j + 1];
        float2 v0 = h2[(size_t)s0 * 64 + lane];
        float2 v1 = h2[(size_t)s1 * 64 + lane];
        ax += c0 * v0.x + c1 * v1.x;
        ay += c0 * v0.y + c1 * v1.y;
    }
    if (j < j1) {
        int s = srcs[j];
        float c = coef[j];
        float2 v = h2[(size_t)s * 64 + lane];
        ax += c * v.x;
        ay += c * v.y;
    }

    float2 bb = ((const float2*)b)[lane];
    float vx = ds * ax + bb.x;
    float vy = ds * ay + bb.y;

    float s = vx + vy;
    #pragma unroll
    for (int off = 32; off; off >>= 1) s += __shfl_xor(s, off);
    float mu = s * (1.0f / 128.0f);
    float dx = vx - mu, dy = vy - mu;
    float q = dx * dx + dy * dy;
    #pragma unroll
    for (int off = 32; off; off >>= 1) q += __shfl_xor(q, off);
    float rs = rsqrtf(q * (1.0f / 128.0f) + LN_EPS);

    float2 g = ((const float2*)gamma)[lane], be = ((const float2*)beta)[lane];
    float2 o;
    o.x = fmaxf(dx * rs * g.x + be.x, 0.f);
    o.y = fmaxf(dy * rs * g.y + be.y, 0.f);
    ((float2*)(out + (size_t)node * 128))[lane] = o;
}

// ---------------- launcher ----------------

extern "C" void kernel_launch(void* const* d_in, const int* in_sizes, int n_in,
                              void* d_out, int out_size, void* d_ws, size_t ws_size,
                              hipStream_t stream) {
    const float* x     = (const float*)d_in[0];
    const int*   ei    = (const int*)d_in[1];   // [2, E] int32
    const float* ew    = (const float*)d_in[2];
    const float* W     = (const float*)d_in[3];
    const float* b     = (const float*)d_in[4];
    const float* gamma = (const float*)d_in[5];
    const float* beta  = (const float*)d_in[6];

    const int n = in_sizes[0] / 128;
    const int E = in_sizes[2];

    float* out = (float*)d_out;

    // workspace layout (bytes):
    //   deg/dis : [0,        0.5MB)   n*4 = 400KB
    //   counts  : [0.5MB,    1.0MB)
    //   row_ptr : [1.0MB,    1.5MB)   (n+1)*4
    //   cursor  : [1.5MB,    2.0MB)
    //   srcs    : [2MB,     15MB)     E*4 = 12.8MB
    //   coef    : [15MB,    28MB)     E*4 = 12.8MB
    //   h       : [28MB,    ~79.2MB)  n*128*4 = 51.2MB
    char* ws = (char*)d_ws;
    float* deg    = (float*)(ws);
    int*   counts = (int*)(ws + (512u << 10));
    int*   rp     = (int*)(ws + (1024u << 10));
    int*   cursor = (int*)(ws + (1536u << 10));
    int*   srcs   = (int*)(ws + (2048u << 10));
    float* coef   = (float*)(ws + (15u << 20));
    float* h      = (float*)(ws + (28u << 20));

    hipMemsetAsync(counts, 0, (size_t)n * sizeof(int), stream);
    hipMemsetAsync(cursor, 0, (size_t)n * sizeof(int), stream);

    fill_deg<<<(n + 255) / 256, 256, 0, stream>>>(deg, n);
    hist_edges<<<(E + 255) / 256, 256, 0, stream>>>(ei, ew, deg, counts, E);
    deg_to_dis<<<(n + 255) / 256, 256, 0, stream>>>(deg, n);
    scan_counts<<<1, 256, 0, stream>>>(counts, rp, n, E);
    sort_edges<<<(E + 255) / 256, 256, 0, stream>>>(ei, ew, deg, rp, cursor, srcs, coef, E);

    dim3 ggrid((n + 63) / 64, 2);
    gemm_xw<<<ggrid, 256, 0, stream>>>(x, W, h, n);

    agg_ln<<<(n + 3) / 4, 256, 0, stream>>>(rp, srcs, coef, h, deg, b, gamma, beta, out, n);
}

// Round 5
// 669.267 us; speedup vs baseline: 34.7668x; 1.7917x over previous
//
#include <hip/hip_runtime.h>

#define LN_EPS 1e-5f
#define FIX_SCALE 33554432.0f          // 2^25
#define FIX_INV   (1.0f / 33554432.0f)
#define MASK40    ((1ULL << 40) - 1)

// ---------------- init packed degree/count: count=0, wsum=1.0 (self-loop) ----------------

__global__ __launch_bounds__(256) void init_packed(unsigned long long* __restrict__ packed, int n) {
    int i = blockIdx.x * 256 + threadIdx.x;
    if (i < n) packed[i] = (1ULL << 25);  // fixed-point 1.0, count 0
}

// ---------------- fused histogram: ONE 64-bit atomic per edge; old>>40 = rank ----------------

__global__ __launch_bounds__(256) void hist_edges_rank(const int* __restrict__ ei,
                                                       const float* __restrict__ w,
                                                       unsigned long long* __restrict__ packed,
                                                       unsigned short* __restrict__ rank, int E) {
    int e = blockIdx.x * 256 + threadIdx.x;
    if (e >= E) return;
    int c = ei[(long long)E + e];
    unsigned long long inc = (1ULL << 40) | (unsigned long long)(w[e] * FIX_SCALE + 0.5f);
    unsigned long long old = atomicAdd(&packed[c], inc);
    rank[e] = (unsigned short)(old >> 40);
}

__global__ __launch_bounds__(256) void hist_edges_plain(const int* __restrict__ ei,
                                                        const float* __restrict__ w,
                                                        unsigned long long* __restrict__ packed, int E) {
    int e = blockIdx.x * 256 + threadIdx.x;
    if (e >= E) return;
    int c = ei[(long long)E + e];
    unsigned long long inc = (1ULL << 40) | (unsigned long long)(w[e] * FIX_SCALE + 0.5f);
    atomicAdd(&packed[c], inc);
}

// ---------------- dis = rsqrt(deg)  (deg >= 1 due to self-loop) ----------------

__global__ __launch_bounds__(256) void deg_to_dis(const unsigned long long* __restrict__ packed,
                                                  float* __restrict__ dis, int n) {
    int i = blockIdx.x * 256 + threadIdx.x;
    if (i < n) {
        float d = (float)(packed[i] & MASK40) * FIX_INV;
        dis[i] = rsqrtf(fmaxf(d, 1e-30f));
    }
}

// ---------------- parallel exclusive scan of counts (3 kernels, 1024 elems/block) ----------------

__global__ __launch_bounds__(256) void scan_bsums(const unsigned long long* __restrict__ packed,
                                                  int* __restrict__ bsum, int n) {
    int base = blockIdx.x * 1024;
    int t = threadIdx.x;
    int s = 0;
    #pragma unroll
    for (int k = 0; k < 4; k++) {
        int i = base + t * 4 + k;
        if (i < n) s += (int)(packed[i] >> 40);
    }
    #pragma unroll
    for (int off = 32; off; off >>= 1) s += __shfl_xor(s, off);
    __shared__ int wsum[4];
    if ((t & 63) == 0) wsum[t >> 6] = s;
    __syncthreads();
    if (t == 0) bsum[blockIdx.x] = wsum[0] + wsum[1] + wsum[2] + wsum[3];
}

__global__ __launch_bounds__(256) void scan_boff(const int* __restrict__ bsum,
                                                 int* __restrict__ boff, int B,
                                                 int* __restrict__ rp, int n, int E) {
    int t = threadIdx.x;
    int v[4]; int loc = 0;
    #pragma unroll
    for (int k = 0; k < 4; k++) {
        int i = t * 4 + k;
        v[k] = (i < B) ? bsum[i] : 0;
        loc += v[k];
    }
    int lane = t & 63, wv = t >> 6;
    int incl = loc;
    #pragma unroll
    for (int off = 1; off < 64; off <<= 1) {
        int tt = __shfl_up(incl, off);
        if (lane >= off) incl += tt;
    }
    __shared__ int wsum[4];
    if (lane == 63) wsum[wv] = incl;
    __syncthreads();
    int woff = 0;
    for (int k = 0; k < wv; k++) woff += wsum[k];
    int run = woff + incl - loc;  // exclusive prefix of this thread's 4
    #pragma unroll
    for (int k = 0; k < 4; k++) {
        int i = t * 4 + k;
        if (i < B) boff[i] = run;
        run += v[k];
    }
    if (t == 0) rp[n] = E;
}

__global__ __launch_bounds__(256) void scan_write(const unsigned long long* __restrict__ packed,
                                                  const int* __restrict__ boff,
                                                  int* __restrict__ rp, int n) {
    int base = blockIdx.x * 1024;
    int t = threadIdx.x;
    int v[4]; int loc = 0;
    #pragma unroll
    for (int k = 0; k < 4; k++) {
        int i = base + t * 4 + k;
        v[k] = (i < n) ? (int)(packed[i] >> 40) : 0;
        loc += v[k];
    }
    int lane = t & 63, wv = t >> 6;
    int incl = loc;
    #pragma unroll
    for (int off = 1; off < 64; off <<= 1) {
        int tt = __shfl_up(incl, off);
        if (lane >= off) incl += tt;
    }
    __shared__ int wsum[4];
    if (lane == 63) wsum[wv] = incl;
    __syncthreads();
    int woff = 0;
    for (int k = 0; k < wv; k++) woff += wsum[k];
    int run = boff[blockIdx.x] + woff + incl - loc;
    #pragma unroll
    for (int k = 0; k < 4; k++) {
        int i = base + t * 4 + k;
        if (i < n) { rp[i] = run; run += v[k]; }
    }
}

// ---------------- counting-sort placement ----------------

__global__ __launch_bounds__(256) void sort_edges_rank(const int* __restrict__ ei,
                                                       const float* __restrict__ w,
                                                       const float* __restrict__ dis,
                                                       const int* __restrict__ rp,
                                                       const unsigned short* __restrict__ rank,
                                                       int2* __restrict__ es, int E) {
    int e = blockIdx.x * 256 + threadIdx.x;
    if (e >= E) return;
    int r = ei[e], c = ei[(long long)E + e];
    int pos = rp[c] + (int)rank[e];
    es[pos] = make_int2(r, __float_as_int(dis[r] * w[e]));
}

__global__ __launch_bounds__(256) void sort_edges_cursor(const int* __restrict__ ei,
                                                         const float* __restrict__ w,
                                                         const float* __restrict__ dis,
                                                         const int* __restrict__ rp,
                                                         int* __restrict__ cursor,
                                                         int2* __restrict__ es, int E) {
    int e = blockIdx.x * 256 + threadIdx.x;
    if (e >= E) return;
    int r = ei[e], c = ei[(long long)E + e];
    int pos = rp[c] + atomicAdd(&cursor[c], 1);
    es[pos] = make_int2(r, __float_as_int(dis[r] * w[e]));
}

// ---------------- h = x @ W  (f32, vector ALU) ----------------

__global__ __launch_bounds__(256) void gemm_xw(const float* __restrict__ x,
                                               const float* __restrict__ W,
                                               float* __restrict__ h, int n) {
    __shared__ float xt[128][64];
    __shared__ float Ws[128][64];
    const int tid = threadIdx.x;
    const int brow = blockIdx.x * 64;
    const int chalf = blockIdx.y;

    for (int i = tid; i < 64 * 32; i += 256) {
        int r = i >> 5, c4 = i & 31, k0 = c4 * 4;
        int gr = brow + r;
        float4 v = make_float4(0.f, 0.f, 0.f, 0.f);
        if (gr < n) v = *(const float4*)(x + (size_t)gr * 128 + k0);
        xt[k0 + 0][r] = v.x; xt[k0 + 1][r] = v.y;
        xt[k0 + 2][r] = v.z; xt[k0 + 3][r] = v.w;
    }
    for (int i = tid; i < 128 * 16; i += 256) {
        int k = i >> 4, c4 = i & 15;
        float4 v = *(const float4*)(W + (size_t)k * 128 + chalf * 64 + c4 * 4);
        *(float4*)&Ws[k][c4 * 4] = v;
    }
    __syncthreads();

    const int r0 = (tid >> 4) * 4;
    const int c0 = (tid & 15) * 4;
    float4 acc0 = make_float4(0, 0, 0, 0), acc1 = acc0, acc2 = acc0, acc3 = acc0;
    #pragma unroll 8
    for (int k = 0; k < 128; k++) {
        float4 xa = *(const float4*)&xt[k][r0];
        float4 wb = *(const float4*)&Ws[k][c0];
        acc0.x += xa.x * wb.x; acc0.y += xa.x * wb.y; acc0.z += xa.x * wb.z; acc0.w += xa.x * wb.w;
        acc1.x += xa.y * wb.x; acc1.y += xa.y * wb.y; acc1.z += xa.y * wb.z; acc1.w += xa.y * wb.w;
        acc2.x += xa.z * wb.x; acc2.y += xa.z * wb.y; acc2.z += xa.z * wb.z; acc2.w += xa.z * wb.w;
        acc3.x += xa.w * wb.x; acc3.y += xa.w * wb.y; acc3.z += xa.w * wb.z; acc3.w += xa.w * wb.w;
    }
    float4 accs[4] = {acc0, acc1, acc2, acc3};
    #pragma unroll
    for (int i = 0; i < 4; i++) {
        int gr = brow + r0 + i;
        if (gr < n) *(float4*)(h + (size_t)gr * 128 + chalf * 64 + c0) = accs[i];
    }
}

// ---------------- CSR gather-aggregate + self-loop + bias + LN + ReLU ----------------

__global__ __launch_bounds__(256) void agg_ln(const int* __restrict__ rp,
                                              const int2* __restrict__ es,
                                              const float* __restrict__ h,
                                              const float* __restrict__ dis,
                                              const float* __restrict__ b,
                                              const float* __restrict__ gamma,
                                              const float* __restrict__ beta,
                                              float* __restrict__ out, int n) {
    const int wave = threadIdx.x >> 6;
    const int lane = threadIdx.x & 63;
    const int node = blockIdx.x * 4 + wave;
    if (node >= n) return;

    const int j0 = rp[node], j1 = rp[node + 1];
    const float ds = dis[node];
    const float2* __restrict__ h2 = (const float2*)h;

    float2 hs = h2[(size_t)node * 64 + lane];
    float ax = ds * hs.x, ay = ds * hs.y;  // self-loop (coef = dis[i]*1)

    int j = j0;
    for (; j + 3 < j1; j += 4) {  // 4-edge unroll: 4 outstanding gathers
        int2 e0 = es[j], e1 = es[j + 1], e2 = es[j + 2], e3 = es[j + 3];
        float2 v0 = h2[(size_t)e0.x * 64 + lane];
        float2 v1 = h2[(size_t)e1.x * 64 + lane];
        float2 v2 = h2[(size_t)e2.x * 64 + lane];
        float2 v3 = h2[(size_t)e3.x * 64 + lane];
        float c0 = __int_as_float(e0.y), c1 = __int_as_float(e1.y);
        float c2 = __int_as_float(e2.y), c3 = __int_as_float(e3.y);
        ax += c0 * v0.x + c1 * v1.x + c2 * v2.x + c3 * v3.x;
        ay += c0 * v0.y + c1 * v1.y + c2 * v2.y + c3 * v3.y;
    }
    for (; j < j1; ++j) {
        int2 e0 = es[j];
        float2 v = h2[(size_t)e0.x * 64 + lane];
        float c = __int_as_float(e0.y);
        ax += c * v.x;
        ay += c * v.y;
    }

    float2 bb = ((const float2*)b)[lane];
    float vx = ds * ax + bb.x;
    float vy = ds * ay + bb.y;

    float s = vx + vy;
    #pragma unroll
    for (int off = 32; off; off >>= 1) s += __shfl_xor(s, off);
    float mu = s * (1.0f / 128.0f);
    float dx = vx - mu, dy = vy - mu;
    float q = dx * dx + dy * dy;
    #pragma unroll
    for (int off = 32; off; off >>= 1) q += __shfl_xor(q, off);
    float rs = rsqrtf(q * (1.0f / 128.0f) + LN_EPS);

    float2 g = ((const float2*)gamma)[lane], be = ((const float2*)beta)[lane];
    float2 o;
    o.x = fmaxf(dx * rs * g.x + be.x, 0.f);
    o.y = fmaxf(dy * rs * g.y + be.y, 0.f);
    ((float2*)(out + (size_t)node * 128))[lane] = o;
}

// ---------------- launcher ----------------

extern "C" void kernel_launch(void* const* d_in, const int* in_sizes, int n_in,
                              void* d_out, int out_size, void* d_ws, size_t ws_size,
                              hipStream_t stream) {
    const float* x     = (const float*)d_in[0];
    const int*   ei    = (const int*)d_in[1];   // [2, E] int32
    const float* ew    = (const float*)d_in[2];
    const float* W     = (const float*)d_in[3];
    const float* b     = (const float*)d_in[4];
    const float* gamma = (const float*)d_in[5];
    const float* beta  = (const float*)d_in[6];

    const int n = in_sizes[0] / 128;
    const int E = in_sizes[2];
    float* out = (float*)d_out;

    char* ws = (char*)d_ws;
    const size_t MB = 1u << 20;

    // common small arrays
    unsigned long long* packed = (unsigned long long*)(ws);            // n*8   <= 0.8MB
    float* dis  = (float*)(ws + 1 * MB);                               // n*4
    int*   rp   = (int*)(ws + 1 * MB + 512 * 1024);                    // (n+1)*4
    int*   bsum = (int*)(ws + 2 * MB);                                 // 4KB
    int*   boff = (int*)(ws + 2 * MB + 64 * 1024);                     // 4KB

    const int B = (n + 1023) / 1024;

    // Path A (rank-based, atomic-free sort): rank @3MB, es @10MB, h @10MB+E*8
    size_t esA_off = 10 * MB;
    size_t hA_off  = esA_off + (size_t)E * 8;
    size_t needA   = hA_off + (size_t)n * 128 * 4;
    // Path B (cursor atomics): cursor @2.25MB, es @3MB, h @3MB+E*8
    size_t esB_off = 3 * MB;
    size_t hB_off  = esB_off + (size_t)E * 8;

    init_packed<<<(n + 255) / 256, 256, 0, stream>>>(packed, n);

    if (ws_size >= needA) {
        unsigned short* rank = (unsigned short*)(ws + 3 * MB);
        int2*  es = (int2*)(ws + esA_off);
        float* h  = (float*)(ws + hA_off);

        hist_edges_rank<<<(E + 255) / 256, 256, 0, stream>>>(ei, ew, packed, rank, E);
        deg_to_dis<<<(n + 255) / 256, 256, 0, stream>>>(packed, dis, n);
        scan_bsums<<<B, 256, 0, stream>>>(packed, bsum, n);
        scan_boff<<<1, 256, 0, stream>>>(bsum, boff, B, rp, n, E);
        scan_write<<<B, 256, 0, stream>>>(packed, boff, rp, n);
        sort_edges_rank<<<(E + 255) / 256, 256, 0, stream>>>(ei, ew, dis, rp, rank, es, E);

        dim3 ggrid((n + 63) / 64, 2);
        gemm_xw<<<ggrid, 256, 0, stream>>>(x, W, h, n);
        agg_ln<<<(n + 3) / 4, 256, 0, stream>>>(rp, es, h, dis, b, gamma, beta, out, n);
    } else {
        int*   cursor = (int*)(ws + 2 * MB + 256 * 1024);
        int2*  es = (int2*)(ws + esB_off);
        float* h  = (float*)(ws + hB_off);

        hipMemsetAsync(cursor, 0, (size_t)n * sizeof(int), stream);
        hist_edges_plain<<<(E + 255) / 256, 256, 0, stream>>>(ei, ew, packed, E);
        deg_to_dis<<<(n + 255) / 256, 256, 0, stream>>>(packed, dis, n);
        scan_bsums<<<B, 256, 0, stream>>>(packed, bsum, n);
        scan_boff<<<1, 256, 0, stream>>>(bsum, boff, B, rp, n, E);
        scan_write<<<B, 256, 0, stream>>>(packed, boff, rp, n);
        sort_edges_cursor<<<(E + 255) / 256, 256, 0, stream>>>(ei, ew, dis, rp, cursor, es, E);

        dim3 ggrid((n + 63) / 64, 2);
        gemm_xw<<<ggrid, 256, 0, stream>>>(x, W, h, n);
        agg_ln<<<(n + 3) / 4, 256, 0, stream>>>(rp, es, h, dis, b, gamma, beta, out, n);
    }
}

// Round 7
// 577.478 us; speedup vs baseline: 40.2930x; 1.1589x over previous
//
#include <hip/hip_runtime.h>

#define LN_EPS 1e-5f
#define FIX_SCALE 33554432.0f          // 2^25
#define FIX_INV   (1.0f / 33554432.0f)
#define MASK40    ((1ULL << 40) - 1)

// pack two f32 -> bf16x2 (round-to-nearest-even), lo in low 16 bits
__device__ __forceinline__ unsigned pack_bf16x2(float lo, float hi) {
    unsigned a = __float_as_uint(lo), b = __float_as_uint(hi);
    a = (a + 0x7FFFu + ((a >> 16) & 1u)) >> 16;
    b = (b + 0x7FFFu + ((b >> 16) & 1u)) >> 16;
    return a | (b << 16);
}

__device__ __forceinline__ float2 unpack_bf16x2(unsigned u) {
    return make_float2(__uint_as_float(u << 16), __uint_as_float(u & 0xFFFF0000u));
}

// ---------------- init packed degree/count: count=0, wsum=1.0 (self-loop) ----------------

__global__ __launch_bounds__(256) void init_packed(unsigned long long* __restrict__ packed, int n) {
    int i = blockIdx.x * 256 + threadIdx.x;
    if (i < n) packed[i] = (1ULL << 25);  // fixed-point 1.0, count 0
}

// ---------------- fused histogram: ONE 64-bit atomic per edge; old>>40 = rank ----------------

__global__ __launch_bounds__(256) void hist_edges_rank(const int* __restrict__ ei,
                                                       const float* __restrict__ w,
                                                       unsigned long long* __restrict__ packed,
                                                       unsigned short* __restrict__ rank, int E) {
    int e = blockIdx.x * 256 + threadIdx.x;
    if (e >= E) return;
    int c = ei[(long long)E + e];
    unsigned long long inc = (1ULL << 40) | (unsigned long long)(w[e] * FIX_SCALE + 0.5f);
    unsigned long long old = atomicAdd(&packed[c], inc);
    rank[e] = (unsigned short)(old >> 40);
}

__global__ __launch_bounds__(256) void hist_edges_plain(const int* __restrict__ ei,
                                                        const float* __restrict__ w,
                                                        unsigned long long* __restrict__ packed, int E) {
    int e = blockIdx.x * 256 + threadIdx.x;
    if (e >= E) return;
    int c = ei[(long long)E + e];
    unsigned long long inc = (1ULL << 40) | (unsigned long long)(w[e] * FIX_SCALE + 0.5f);
    atomicAdd(&packed[c], inc);
}

// ---------------- dis = rsqrt(deg) ----------------

__global__ __launch_bounds__(256) void deg_to_dis(const unsigned long long* __restrict__ packed,
                                                  float* __restrict__ dis, int n) {
    int i = blockIdx.x * 256 + threadIdx.x;
    if (i < n) {
        float d = (float)(packed[i] & MASK40) * FIX_INV;
        dis[i] = rsqrtf(fmaxf(d, 1e-30f));
    }
}

// ---------------- parallel exclusive scan of counts (3 kernels, 1024 elems/block) ----------------

__global__ __launch_bounds__(256) void scan_bsums(const unsigned long long* __restrict__ packed,
                                                  int* __restrict__ bsum, int n) {
    int base = blockIdx.x * 1024;
    int t = threadIdx.x;
    int s = 0;
    #pragma unroll
    for (int k = 0; k < 4; k++) {
        int i = base + t * 4 + k;
        if (i < n) s += (int)(packed[i] >> 40);
    }
    #pragma unroll
    for (int off = 32; off; off >>= 1) s += __shfl_xor(s, off);
    __shared__ int wsum[4];
    if ((t & 63) == 0) wsum[t >> 6] = s;
    __syncthreads();
    if (t == 0) bsum[blockIdx.x] = wsum[0] + wsum[1] + wsum[2] + wsum[3];
}

__global__ __launch_bounds__(256) void scan_boff(const int* __restrict__ bsum,
                                                 int* __restrict__ boff, int B,
                                                 int* __restrict__ rp, int n, int E) {
    int t = threadIdx.x;
    int v[4]; int loc = 0;
    #pragma unroll
    for (int k = 0; k < 4; k++) {
        int i = t * 4 + k;
        v[k] = (i < B) ? bsum[i] : 0;
        loc += v[k];
    }
    int lane = t & 63, wv = t >> 6;
    int incl = loc;
    #pragma unroll
    for (int off = 1; off < 64; off <<= 1) {
        int tt = __shfl_up(incl, off);
        if (lane >= off) incl += tt;
    }
    __shared__ int wsum[4];
    if (lane == 63) wsum[wv] = incl;
    __syncthreads();
    int woff = 0;
    for (int k = 0; k < wv; k++) woff += wsum[k];
    int run = woff + incl - loc;
    #pragma unroll
    for (int k = 0; k < 4; k++) {
        int i = t * 4 + k;
        if (i < B) boff[i] = run;
        run += v[k];
    }
    if (t == 0) rp[n] = E;
}

__global__ __launch_bounds__(256) void scan_write(const unsigned long long* __restrict__ packed,
                                                  const int* __restrict__ boff,
                                                  int* __restrict__ rp, int n) {
    int base = blockIdx.x * 1024;
    int t = threadIdx.x;
    int v[4]; int loc = 0;
    #pragma unroll
    for (int k = 0; k < 4; k++) {
        int i = base + t * 4 + k;
        v[k] = (i < n) ? (int)(packed[i] >> 40) : 0;
        loc += v[k];
    }
    int lane = t & 63, wv = t >> 6;
    int incl = loc;
    #pragma unroll
    for (int off = 1; off < 64; off <<= 1) {
        int tt = __shfl_up(incl, off);
        if (lane >= off) incl += tt;
    }
    __shared__ int wsum[4];
    if (lane == 63) wsum[wv] = incl;
    __syncthreads();
    int woff = 0;
    for (int k = 0; k < wv; k++) woff += wsum[k];
    int run = boff[blockIdx.x] + woff + incl - loc;
    #pragma unroll
    for (int k = 0; k < 4; k++) {
        int i = base + t * 4 + k;
        if (i < n) { rp[i] = run; run += v[k]; }
    }
}

// ---------------- counting-sort placement ----------------

__global__ __launch_bounds__(256) void sort_edges_rank(const int* __restrict__ ei,
                                                       const float* __restrict__ w,
                                                       const float* __restrict__ dis,
                                                       const int* __restrict__ rp,
                                                       const unsigned short* __restrict__ rank,
                                                       int2* __restrict__ es, int E) {
    int e = blockIdx.x * 256 + threadIdx.x;
    if (e >= E) return;
    int r = ei[e], c = ei[(long long)E + e];
    int pos = rp[c] + (int)rank[e];
    es[pos] = make_int2(r, __float_as_int(dis[r] * w[e]));
}

__global__ __launch_bounds__(256) void sort_edges_cursor(const int* __restrict__ ei,
                                                         const float* __restrict__ w,
                                                         const float* __restrict__ dis,
                                                         const int* __restrict__ rp,
                                                         int* __restrict__ cursor,
                                                         int2* __restrict__ es, int E) {
    int e = blockIdx.x * 256 + threadIdx.x;
    if (e >= E) return;
    int r = ei[e], c = ei[(long long)E + e];
    int pos = rp[c] + atomicAdd(&cursor[c], 1);
    es[pos] = make_int2(r, __float_as_int(dis[r] * w[e]));
}

// ---------------- h = x @ W  (f32 compute, bf16 output) ----------------

__global__ __launch_bounds__(256) void gemm_xw(const float* __restrict__ x,
                                               const float* __restrict__ W,
                                               unsigned* __restrict__ hb, int n) {
    __shared__ float xt[128][64];
    __shared__ float Ws[128][64];
    const int tid = threadIdx.x;
    const int brow = blockIdx.x * 64;
    const int chalf = blockIdx.y;

    for (int i = tid; i < 64 * 32; i += 256) {
        int r = i >> 5, c4 = i & 31, k0 = c4 * 4;
        int gr = brow + r;
        float4 v = make_float4(0.f, 0.f, 0.f, 0.f);
        if (gr < n) v = *(const float4*)(x + (size_t)gr * 128 + k0);
        xt[k0 + 0][r] = v.x; xt[k0 + 1][r] = v.y;
        xt[k0 + 2][r] = v.z; xt[k0 + 3][r] = v.w;
    }
    for (int i = tid; i < 128 * 16; i += 256) {
        int k = i >> 4, c4 = i & 15;
        float4 v = *(const float4*)(W + (size_t)k * 128 + chalf * 64 + c4 * 4);
        *(float4*)&Ws[k][c4 * 4] = v;
    }
    __syncthreads();

    const int r0 = (tid >> 4) * 4;
    const int c0 = (tid & 15) * 4;
    float4 acc0 = make_float4(0, 0, 0, 0), acc1 = acc0, acc2 = acc0, acc3 = acc0;
    #pragma unroll 8
    for (int k = 0; k < 128; k++) {
        float4 xa = *(const float4*)&xt[k][r0];
        float4 wb = *(const float4*)&Ws[k][c0];
        acc0.x += xa.x * wb.x; acc0.y += xa.x * wb.y; acc0.z += xa.x * wb.z; acc0.w += xa.x * wb.w;
        acc1.x += xa.y * wb.x; acc1.y += xa.y * wb.y; acc1.z += xa.y * wb.z; acc1.w += xa.y * wb.w;
        acc2.x += xa.z * wb.x; acc2.y += xa.z * wb.y; acc2.z += xa.z * wb.z; acc2.w += xa.z * wb.w;
        acc3.x += xa.w * wb.x; acc3.y += xa.w * wb.y; acc3.z += xa.w * wb.z; acc3.w += xa.w * wb.w;
    }
    float4 accs[4] = {acc0, acc1, acc2, acc3};
    #pragma unroll
    for (int i = 0; i < 4; i++) {
        int gr = brow + r0 + i;
        if (gr < n) {
            uint2 p;
            p.x = pack_bf16x2(accs[i].x, accs[i].y);
            p.y = pack_bf16x2(accs[i].z, accs[i].w);
            *(uint2*)(hb + (size_t)gr * 64 + (chalf * 64 + c0) / 2) = p;
        }
    }
}

// ---------------- CSR gather-aggregate + self-loop + bias + LN + ReLU ----------------
// one wave per node; lane l owns features 2l, 2l+1 (one bf16x2 uint per lane).

__global__ __launch_bounds__(256) void agg_ln(const int* __restrict__ rp,
                                              const int2* __restrict__ es,
                                              const unsigned* __restrict__ hb,
                                              const float* __restrict__ dis,
                                              const float* __restrict__ b,
                                              const float* __restrict__ gamma,
                                              const float* __restrict__ beta,
                                              float* __restrict__ out, int n) {
    const int wave = threadIdx.x >> 6;
    const int lane = threadIdx.x & 63;
    const int node = blockIdx.x * 4 + wave;
    if (node >= n) return;

    const int j0 = rp[node], j1 = rp[node + 1];
    const float ds = dis[node];

    float2 hs = unpack_bf16x2(hb[(size_t)node * 64 + lane]);
    float ax = ds * hs.x, ay = ds * hs.y;  // self-loop (coef = dis[i]*1)

    int j = j0;
    for (; j + 7 < j1; j += 8) {  // 8 outstanding gathers
        int2 ee[8]; unsigned uu[8];
        #pragma unroll
        for (int k = 0; k < 8; k++) ee[k] = es[j + k];
        #pragma unroll
        for (int k = 0; k < 8; k++) uu[k] = hb[(size_t)ee[k].x * 64 + lane];
        #pragma unroll
        for (int k = 0; k < 8; k++) {
            float c = __int_as_float(ee[k].y);
            float2 v = unpack_bf16x2(uu[k]);
            ax += c * v.x;
            ay += c * v.y;
        }
    }
    for (; j < j1; ++j) {
        int2 e0 = es[j];
        float2 v = unpack_bf16x2(hb[(size_t)e0.x * 64 + lane]);
        float c = __int_as_float(e0.y);
        ax += c * v.x;
        ay += c * v.y;
    }

    float2 bb = ((const float2*)b)[lane];
    float vx = ds * ax + bb.x;
    float vy = ds * ay + bb.y;

    float s = vx + vy;
    #pragma unroll
    for (int off = 32; off; off >>= 1) s += __shfl_xor(s, off);
    float mu = s * (1.0f / 128.0f);
    float dx = vx - mu, dy = vy - mu;
    float q = dx * dx + dy * dy;
    #pragma unroll
    for (int off = 32; off; off >>= 1) q += __shfl_xor(q, off);
    float rs = rsqrtf(q * (1.0f / 128.0f) + LN_EPS);

    float2 g = ((const float2*)gamma)[lane], be = ((const float2*)beta)[lane];
    float2 o;
    o.x = fmaxf(dx * rs * g.x + be.x, 0.f);
    o.y = fmaxf(dy * rs * g.y + be.y, 0.f);
    ((float2*)(out + (size_t)node * 128))[lane] = o;
}

// ---------------- launcher ----------------

extern "C" void kernel_launch(void* const* d_in, const int* in_sizes, int n_in,
                              void* d_out, int out_size, void* d_ws, size_t ws_size,
                              hipStream_t stream) {
    const float* x     = (const float*)d_in[0];
    const int*   ei    = (const int*)d_in[1];   // [2, E] int32
    const float* ew    = (const float*)d_in[2];
    const float* W     = (const float*)d_in[3];
    const float* b     = (const float*)d_in[4];
    const float* gamma = (const float*)d_in[5];
    const float* beta  = (const float*)d_in[6];

    const int n = in_sizes[0] / 128;
    const int E = in_sizes[2];
    float* out = (float*)d_out;

    char* ws = (char*)d_ws;
    const size_t MB = 1u << 20;

    unsigned long long* packed = (unsigned long long*)(ws);            // n*8
    float* dis  = (float*)(ws + 1 * MB);                               // n*4
    int*   rp   = (int*)(ws + 1 * MB + 512 * 1024);                    // (n+1)*4
    int*   bsum = (int*)(ws + 2 * MB);
    int*   boff = (int*)(ws + 2 * MB + 64 * 1024);

    const int B = (n + 1023) / 1024;

    // Path A (rank-based, atomic-free sort): rank @3MB, es @10MB, h(bf16) after es
    size_t esA_off = 10 * MB;
    size_t hA_off  = esA_off + (size_t)E * 8;
    size_t needA   = hA_off + (size_t)n * 128 * 2;
    // Path B (cursor atomics)
    size_t esB_off = 3 * MB;
    size_t hB_off  = esB_off + (size_t)E * 8;

    init_packed<<<(n + 255) / 256, 256, 0, stream>>>(packed, n);

    if (ws_size >= needA) {
        unsigned short* rank = (unsigned short*)(ws + 3 * MB);
        int2*     es = (int2*)(ws + esA_off);
        unsigned* hb = (unsigned*)(ws + hA_off);

        hist_edges_rank<<<(E + 255) / 256, 256, 0, stream>>>(ei, ew, packed, rank, E);
        deg_to_dis<<<(n + 255) / 256, 256, 0, stream>>>(packed, dis, n);
        scan_bsums<<<B, 256, 0, stream>>>(packed, bsum, n);
        scan_boff<<<1, 256, 0, stream>>>(bsum, boff, B, rp, n, E);
        scan_write<<<B, 256, 0, stream>>>(packed, boff, rp, n);
        sort_edges_rank<<<(E + 255) / 256, 256, 0, stream>>>(ei, ew, dis, rp, rank, es, E);

        dim3 ggrid((n + 63) / 64, 2);
        gemm_xw<<<ggrid, 256, 0, stream>>>(x, W, hb, n);
        agg_ln<<<(n + 3) / 4, 256, 0, stream>>>(rp, es, hb, dis, b, gamma, beta, out, n);
    } else {
        int*      cursor = (int*)(ws + 2 * MB + 256 * 1024);
        int2*     es = (int2*)(ws + esB_off);
        unsigned* hb = (unsigned*)(ws + hB_off);

        hipMemsetAsync(cursor, 0, (size_t)n * sizeof(int), stream);
        hist_edges_plain<<<(E + 255) / 256, 256, 0, stream>>>(ei, ew, packed, E);
        deg_to_dis<<<(n + 255) / 256, 256, 0, stream>>>(packed, dis, n);
        scan_bsums<<<B, 256, 0, stream>>>(packed, bsum, n);
        scan_boff<<<1, 256, 0, stream>>>(bsum, boff, B, rp, n, E);
        scan_write<<<B, 256, 0, stream>>>(packed, boff, rp, n);
        sort_edges_cursor<<<(E + 255) / 256, 256, 0, stream>>>(ei, ew, dis, rp, cursor, es, E);

        dim3 ggrid((n + 63) / 64, 2);
        gemm_xw<<<ggrid, 256, 0, stream>>>(x, W, hb, n);
        agg_ln<<<(n + 3) / 4, 256, 0, stream>>>(rp, es, hb, dis, b, gamma, beta, out, n);
    }
}

// Round 8
// 556.262 us; speedup vs baseline: 41.8297x; 1.0381x over previous
//
#include <hip/hip_runtime.h>

#define LN_EPS 1e-5f
#define FIX_SCALE 33554432.0f          // 2^25
#define FIX_INV   (1.0f / 33554432.0f)
#define MASK40    ((1ULL << 40) - 1)

// pack two f32 -> bf16x2 (round-to-nearest-even), lo in low 16 bits
__device__ __forceinline__ unsigned pack_bf16x2(float lo, float hi) {
    unsigned a = __float_as_uint(lo), b = __float_as_uint(hi);
    a = (a + 0x7FFFu + ((a >> 16) & 1u)) >> 16;
    b = (b + 0x7FFFu + ((b >> 16) & 1u)) >> 16;
    return a | (b << 16);
}

__device__ __forceinline__ float2 unpack_bf16x2(unsigned u) {
    return make_float2(__uint_as_float(u << 16), __uint_as_float(u & 0xFFFF0000u));
}

// ---------------- init packed degree/count: count=0, wsum=1.0 (self-loop) ----------------

__global__ __launch_bounds__(256) void init_packed(unsigned long long* __restrict__ packed, int n) {
    int i = blockIdx.x * 256 + threadIdx.x;
    if (i < n) packed[i] = (1ULL << 25);  // fixed-point 1.0, count 0
}

// ---------------- FUSED: hist (atomic-bound) + gemm (compute-bound) ----------------
// blocks [0, histBlocks): one packed 64-bit atomic per edge; old>>40 = rank within segment.
// blocks [histBlocks, ...): 64x64 tile of h = x @ W, output packed bf16.
// hist blocks ignore the LDS; 64KB/block caps residency at 2 blocks/CU which still
// leaves ~131k threads in flight for the atomic stream (needs ~33k at 22 G/s x 1.5us).

__global__ __launch_bounds__(256) void gemm_hist(const float* __restrict__ x,
                                                 const float* __restrict__ W,
                                                 unsigned* __restrict__ hb, int n,
                                                 const int* __restrict__ ei,
                                                 const float* __restrict__ ew,
                                                 unsigned long long* __restrict__ packed,
                                                 unsigned short* __restrict__ rank,
                                                 int E, int histBlocks) {
    __shared__ float xt[128][64];
    __shared__ float Ws[128][64];
    const int tid = threadIdx.x;

    if ((int)blockIdx.x < histBlocks) {
        int e = blockIdx.x * 256 + tid;
        if (e < E) {
            int c = ei[(long long)E + e];
            unsigned long long inc = (1ULL << 40) | (unsigned long long)(ew[e] * FIX_SCALE + 0.5f);
            unsigned long long old = atomicAdd(&packed[c], inc);
            rank[e] = (unsigned short)(old >> 40);
        }
        return;  // block-uniform exit before any __syncthreads
    }

    const int g = (int)blockIdx.x - histBlocks;
    const int brow = (g >> 1) * 64;
    const int chalf = g & 1;

    for (int i = tid; i < 64 * 32; i += 256) {
        int r = i >> 5, c4 = i & 31, k0 = c4 * 4;
        int gr = brow + r;
        float4 v = make_float4(0.f, 0.f, 0.f, 0.f);
        if (gr < n) v = *(const float4*)(x + (size_t)gr * 128 + k0);
        xt[k0 + 0][r] = v.x; xt[k0 + 1][r] = v.y;
        xt[k0 + 2][r] = v.z; xt[k0 + 3][r] = v.w;
    }
    for (int i = tid; i < 128 * 16; i += 256) {
        int k = i >> 4, c4 = i & 15;
        float4 v = *(const float4*)(W + (size_t)k * 128 + chalf * 64 + c4 * 4);
        *(float4*)&Ws[k][c4 * 4] = v;
    }
    __syncthreads();

    const int r0 = (tid >> 4) * 4;
    const int c0 = (tid & 15) * 4;
    float4 acc0 = make_float4(0, 0, 0, 0), acc1 = acc0, acc2 = acc0, acc3 = acc0;
    #pragma unroll 8
    for (int k = 0; k < 128; k++) {
        float4 xa = *(const float4*)&xt[k][r0];
        float4 wb = *(const float4*)&Ws[k][c0];
        acc0.x += xa.x * wb.x; acc0.y += xa.x * wb.y; acc0.z += xa.x * wb.z; acc0.w += xa.x * wb.w;
        acc1.x += xa.y * wb.x; acc1.y += xa.y * wb.y; acc1.z += xa.y * wb.z; acc1.w += xa.y * wb.w;
        acc2.x += xa.z * wb.x; acc2.y += xa.z * wb.y; acc2.z += xa.z * wb.z; acc2.w += xa.z * wb.w;
        acc3.x += xa.w * wb.x; acc3.y += xa.w * wb.y; acc3.z += xa.w * wb.z; acc3.w += xa.w * wb.w;
    }
    float4 accs[4] = {acc0, acc1, acc2, acc3};
    #pragma unroll
    for (int i = 0; i < 4; i++) {
        int gr = brow + r0 + i;
        if (gr < n) {
            uint2 p;
            p.x = pack_bf16x2(accs[i].x, accs[i].y);
            p.y = pack_bf16x2(accs[i].z, accs[i].w);
            *(uint2*)(hb + (size_t)gr * 64 + (chalf * 64 + c0) / 2) = p;
        }
    }
}

// plain hist (fallback path B, no rank)
__global__ __launch_bounds__(256) void hist_edges_plain(const int* __restrict__ ei,
                                                        const float* __restrict__ w,
                                                        unsigned long long* __restrict__ packed, int E) {
    int e = blockIdx.x * 256 + threadIdx.x;
    if (e >= E) return;
    int c = ei[(long long)E + e];
    unsigned long long inc = (1ULL << 40) | (unsigned long long)(w[e] * FIX_SCALE + 0.5f);
    atomicAdd(&packed[c], inc);
}

// standalone gemm (fallback path B)
__global__ __launch_bounds__(256) void gemm_xw(const float* __restrict__ x,
                                               const float* __restrict__ W,
                                               unsigned* __restrict__ hb, int n) {
    __shared__ float xt[128][64];
    __shared__ float Ws[128][64];
    const int tid = threadIdx.x;
    const int brow = blockIdx.x * 64;
    const int chalf = blockIdx.y;

    for (int i = tid; i < 64 * 32; i += 256) {
        int r = i >> 5, c4 = i & 31, k0 = c4 * 4;
        int gr = brow + r;
        float4 v = make_float4(0.f, 0.f, 0.f, 0.f);
        if (gr < n) v = *(const float4*)(x + (size_t)gr * 128 + k0);
        xt[k0 + 0][r] = v.x; xt[k0 + 1][r] = v.y;
        xt[k0 + 2][r] = v.z; xt[k0 + 3][r] = v.w;
    }
    for (int i = tid; i < 128 * 16; i += 256) {
        int k = i >> 4, c4 = i & 15;
        float4 v = *(const float4*)(W + (size_t)k * 128 + chalf * 64 + c4 * 4);
        *(float4*)&Ws[k][c4 * 4] = v;
    }
    __syncthreads();

    const int r0 = (tid >> 4) * 4;
    const int c0 = (tid & 15) * 4;
    float4 acc0 = make_float4(0, 0, 0, 0), acc1 = acc0, acc2 = acc0, acc3 = acc0;
    #pragma unroll 8
    for (int k = 0; k < 128; k++) {
        float4 xa = *(const float4*)&xt[k][r0];
        float4 wb = *(const float4*)&Ws[k][c0];
        acc0.x += xa.x * wb.x; acc0.y += xa.x * wb.y; acc0.z += xa.x * wb.z; acc0.w += xa.x * wb.w;
        acc1.x += xa.y * wb.x; acc1.y += xa.y * wb.y; acc1.z += xa.y * wb.z; acc1.w += xa.y * wb.w;
        acc2.x += xa.z * wb.x; acc2.y += xa.z * wb.y; acc2.z += xa.z * wb.z; acc2.w += xa.z * wb.w;
        acc3.x += xa.w * wb.x; acc3.y += xa.w * wb.y; acc3.z += xa.w * wb.z; acc3.w += xa.w * wb.w;
    }
    float4 accs[4] = {acc0, acc1, acc2, acc3};
    #pragma unroll
    for (int i = 0; i < 4; i++) {
        int gr = brow + r0 + i;
        if (gr < n) {
            uint2 p;
            p.x = pack_bf16x2(accs[i].x, accs[i].y);
            p.y = pack_bf16x2(accs[i].z, accs[i].w);
            *(uint2*)(hb + (size_t)gr * 64 + (chalf * 64 + c0) / 2) = p;
        }
    }
}

// ---------------- scan pass 1 (fused with dis = rsqrt(deg)) ----------------

__global__ __launch_bounds__(256) void scan_bsums_dis(const unsigned long long* __restrict__ packed,
                                                      int* __restrict__ bsum,
                                                      float* __restrict__ dis, int n) {
    int base = blockIdx.x * 1024;
    int t = threadIdx.x;
    int s = 0;
    #pragma unroll
    for (int k = 0; k < 4; k++) {
        int i = base + t * 4 + k;
        if (i < n) {
            unsigned long long p = packed[i];
            s += (int)(p >> 40);
            float d = (float)(p & MASK40) * FIX_INV;
            dis[i] = rsqrtf(fmaxf(d, 1e-30f));
        }
    }
    #pragma unroll
    for (int off = 32; off; off >>= 1) s += __shfl_xor(s, off);
    __shared__ int wsum[4];
    if ((t & 63) == 0) wsum[t >> 6] = s;
    __syncthreads();
    if (t == 0) bsum[blockIdx.x] = wsum[0] + wsum[1] + wsum[2] + wsum[3];
}

__global__ __launch_bounds__(256) void scan_boff(const int* __restrict__ bsum,
                                                 int* __restrict__ boff, int B,
                                                 int* __restrict__ rp, int n, int E) {
    int t = threadIdx.x;
    int v[4]; int loc = 0;
    #pragma unroll
    for (int k = 0; k < 4; k++) {
        int i = t * 4 + k;
        v[k] = (i < B) ? bsum[i] : 0;
        loc += v[k];
    }
    int lane = t & 63, wv = t >> 6;
    int incl = loc;
    #pragma unroll
    for (int off = 1; off < 64; off <<= 1) {
        int tt = __shfl_up(incl, off);
        if (lane >= off) incl += tt;
    }
    __shared__ int wsum[4];
    if (lane == 63) wsum[wv] = incl;
    __syncthreads();
    int woff = 0;
    for (int k = 0; k < wv; k++) woff += wsum[k];
    int run = woff + incl - loc;
    #pragma unroll
    for (int k = 0; k < 4; k++) {
        int i = t * 4 + k;
        if (i < B) boff[i] = run;
        run += v[k];
    }
    if (t == 0) rp[n] = E;
}

__global__ __launch_bounds__(256) void scan_write(const unsigned long long* __restrict__ packed,
                                                  const int* __restrict__ boff,
                                                  int* __restrict__ rp, int n) {
    int base = blockIdx.x * 1024;
    int t = threadIdx.x;
    int v[4]; int loc = 0;
    #pragma unroll
    for (int k = 0; k < 4; k++) {
        int i = base + t * 4 + k;
        v[k] = (i < n) ? (int)(packed[i] >> 40) : 0;
        loc += v[k];
    }
    int lane = t & 63, wv = t >> 6;
    int incl = loc;
    #pragma unroll
    for (int off = 1; off < 64; off <<= 1) {
        int tt = __shfl_up(incl, off);
        if (lane >= off) incl += tt;
    }
    __shared__ int wsum[4];
    if (lane == 63) wsum[wv] = incl;
    __syncthreads();
    int woff = 0;
    for (int k = 0; k < wv; k++) woff += wsum[k];
    int run = boff[blockIdx.x] + woff + incl - loc;
    #pragma unroll
    for (int k = 0; k < 4; k++) {
        int i = base + t * 4 + k;
        if (i < n) { rp[i] = run; run += v[k]; }
    }
}

// ---------------- counting-sort placement ----------------

__global__ __launch_bounds__(256) void sort_edges_rank(const int* __restrict__ ei,
                                                       const float* __restrict__ w,
                                                       const float* __restrict__ dis,
                                                       const int* __restrict__ rp,
                                                       const unsigned short* __restrict__ rank,
                                                       int2* __restrict__ es, int E) {
    int e = blockIdx.x * 256 + threadIdx.x;
    if (e >= E) return;
    int r = ei[e], c = ei[(long long)E + e];
    int pos = rp[c] + (int)rank[e];
    es[pos] = make_int2(r, __float_as_int(dis[r] * w[e]));
}

__global__ __launch_bounds__(256) void sort_edges_cursor(const int* __restrict__ ei,
                                                         const float* __restrict__ w,
                                                         const float* __restrict__ dis,
                                                         const int* __restrict__ rp,
                                                         int* __restrict__ cursor,
                                                         int2* __restrict__ es, int E) {
    int e = blockIdx.x * 256 + threadIdx.x;
    if (e >= E) return;
    int r = ei[e], c = ei[(long long)E + e];
    int pos = rp[c] + atomicAdd(&cursor[c], 1);
    es[pos] = make_int2(r, __float_as_int(dis[r] * w[e]));
}

// ---------------- CSR gather-aggregate + self-loop + bias + LN + ReLU ----------------
// one wave per node; lane l owns features 2l, 2l+1 (one bf16x2 uint per lane).

__global__ __launch_bounds__(256) void agg_ln(const int* __restrict__ rp,
                                              const int2* __restrict__ es,
                                              const unsigned* __restrict__ hb,
                                              const float* __restrict__ dis,
                                              const float* __restrict__ b,
                                              const float* __restrict__ gamma,
                                              const float* __restrict__ beta,
                                              float* __restrict__ out, int n) {
    const int wave = threadIdx.x >> 6;
    const int lane = threadIdx.x & 63;
    const int node = blockIdx.x * 4 + wave;
    if (node >= n) return;

    const int j0 = rp[node], j1 = rp[node + 1];
    const float ds = dis[node];

    float2 hs = unpack_bf16x2(hb[(size_t)node * 64 + lane]);
    float ax = ds * hs.x, ay = ds * hs.y;  // self-loop (coef = dis[i]*1)

    int j = j0;
    for (; j + 7 < j1; j += 8) {  // 8 outstanding gathers
        int2 ee[8]; unsigned uu[8];
        #pragma unroll
        for (int k = 0; k < 8; k++) ee[k] = es[j + k];
        #pragma unroll
        for (int k = 0; k < 8; k++) uu[k] = hb[(size_t)ee[k].x * 64 + lane];
        #pragma unroll
        for (int k = 0; k < 8; k++) {
            float c = __int_as_float(ee[k].y);
            float2 v = unpack_bf16x2(uu[k]);
            ax += c * v.x;
            ay += c * v.y;
        }
    }
    for (; j < j1; ++j) {
        int2 e0 = es[j];
        float2 v = unpack_bf16x2(hb[(size_t)e0.x * 64 + lane]);
        float c = __int_as_float(e0.y);
        ax += c * v.x;
        ay += c * v.y;
    }

    float2 bb = ((const float2*)b)[lane];
    float vx = ds * ax + bb.x;
    float vy = ds * ay + bb.y;

    float s = vx + vy;
    #pragma unroll
    for (int off = 32; off; off >>= 1) s += __shfl_xor(s, off);
    float mu = s * (1.0f / 128.0f);
    float dx = vx - mu, dy = vy - mu;
    float q = dx * dx + dy * dy;
    #pragma unroll
    for (int off = 32; off; off >>= 1) q += __shfl_xor(q, off);
    float rs = rsqrtf(q * (1.0f / 128.0f) + LN_EPS);

    float2 g = ((const float2*)gamma)[lane], be = ((const float2*)beta)[lane];
    float2 o;
    o.x = fmaxf(dx * rs * g.x + be.x, 0.f);
    o.y = fmaxf(dy * rs * g.y + be.y, 0.f);
    ((float2*)(out + (size_t)node * 128))[lane] = o;
}

// ---------------- launcher ----------------

extern "C" void kernel_launch(void* const* d_in, const int* in_sizes, int n_in,
                              void* d_out, int out_size, void* d_ws, size_t ws_size,
                              hipStream_t stream) {
    const float* x     = (const float*)d_in[0];
    const int*   ei    = (const int*)d_in[1];   // [2, E] int32
    const float* ew    = (const float*)d_in[2];
    const float* W     = (const float*)d_in[3];
    const float* b     = (const float*)d_in[4];
    const float* gamma = (const float*)d_in[5];
    const float* beta  = (const float*)d_in[6];

    const int n = in_sizes[0] / 128;
    const int E = in_sizes[2];
    float* out = (float*)d_out;

    char* ws = (char*)d_ws;
    const size_t MB = 1u << 20;

    unsigned long long* packed = (unsigned long long*)(ws);            // n*8
    float* dis  = (float*)(ws + 1 * MB);                               // n*4
    int*   rp   = (int*)(ws + 1 * MB + 512 * 1024);                    // (n+1)*4
    int*   bsum = (int*)(ws + 2 * MB);
    int*   boff = (int*)(ws + 2 * MB + 64 * 1024);

    const int B = (n + 1023) / 1024;

    // Path A (rank-based, atomic-free sort): rank @3MB, es @10MB, h(bf16) after es
    size_t esA_off = 10 * MB;
    size_t hA_off  = esA_off + (size_t)E * 8;
    size_t needA   = hA_off + (size_t)n * 128 * 2;
    // Path B (cursor atomics)
    size_t esB_off = 3 * MB;
    size_t hB_off  = esB_off + (size_t)E * 8;

    init_packed<<<(n + 255) / 256, 256, 0, stream>>>(packed, n);

    if (ws_size >= needA) {
        unsigned short* rank = (unsigned short*)(ws + 3 * MB);
        int2*     es = (int2*)(ws + esA_off);
        unsigned* hb = (unsigned*)(ws + hA_off);

        // fused hist (atomic stream) + gemm (compute) — hist blocks first
        const int histBlocks = (E + 255) / 256;
        const int gemmBlocks = ((n + 63) / 64) * 2;
        gemm_hist<<<histBlocks + gemmBlocks, 256, 0, stream>>>(
            x, W, hb, n, ei, ew, packed, rank, E, histBlocks);

        scan_bsums_dis<<<B, 256, 0, stream>>>(packed, bsum, dis, n);
        scan_boff<<<1, 256, 0, stream>>>(bsum, boff, B, rp, n, E);
        scan_write<<<B, 256, 0, stream>>>(packed, boff, rp, n);
        sort_edges_rank<<<(E + 255) / 256, 256, 0, stream>>>(ei, ew, dis, rp, rank, es, E);

        agg_ln<<<(n + 3) / 4, 256, 0, stream>>>(rp, es, hb, dis, b, gamma, beta, out, n);
    } else {
        int*      cursor = (int*)(ws + 2 * MB + 256 * 1024);
        int2*     es = (int2*)(ws + esB_off);
        unsigned* hb = (unsigned*)(ws + hB_off);

        hipMemsetAsync(cursor, 0, (size_t)n * sizeof(int), stream);
        hist_edges_plain<<<(E + 255) / 256, 256, 0, stream>>>(ei, ew, packed, E);
        scan_bsums_dis<<<B, 256, 0, stream>>>(packed, bsum, dis, n);
        scan_boff<<<1, 256, 0, stream>>>(bsum, boff, B, rp, n, E);
        scan_write<<<B, 256, 0, stream>>>(packed, boff, rp, n);
        sort_edges_cursor<<<(E + 255) / 256, 256, 0, stream>>>(ei, ew, dis, rp, cursor, es, E);

        dim3 ggrid((n + 63) / 64, 2);
        gemm_xw<<<ggrid, 256, 0, stream>>>(x, W, hb, n);
        agg_ln<<<(n + 3) / 4, 256, 0, stream>>>(rp, es, hb, dis, b, gamma, beta, out, n);
    }
}

// Round 9
// 487.203 us; speedup vs baseline: 47.7590x; 1.1417x over previous
//
#include <hip/hip_runtime.h>

#define LN_EPS 1e-5f
#define FIX_SCALE 33554432.0f          // 2^25
#define FIX_INV   (1.0f / 33554432.0f)
#define MASK40    ((1ULL << 40) - 1)

// pack two f32 -> bf16x2 (round-to-nearest-even), lo in low 16 bits
__device__ __forceinline__ unsigned pack_bf16x2(float lo, float hi) {
    unsigned a = __float_as_uint(lo), b = __float_as_uint(hi);
    a = (a + 0x7FFFu + ((a >> 16) & 1u)) >> 16;
    b = (b + 0x7FFFu + ((b >> 16) & 1u)) >> 16;
    return a | (b << 16);
}

__device__ __forceinline__ float2 unpack_bf16x2(unsigned u) {
    return make_float2(__uint_as_float(u << 16), __uint_as_float(u & 0xFFFF0000u));
}

// ---------------- init packed degree/count: count=0, wsum=1.0 (self-loop) ----------------

__global__ __launch_bounds__(256) void init_packed(unsigned long long* __restrict__ packed, int n) {
    int i = blockIdx.x * 256 + threadIdx.x;
    if (i < n) packed[i] = (1ULL << 25);  // fixed-point 1.0, count 0
}

// ---------------- FUSED (v2): hist + gemm, INTERLEAVED roles, small LDS ----------------
// Roles interleaved by blockIdx (1 gemm : ~4 hist) so both streams run concurrently.
// gemm: 64x64 tile, K in 4 chunks of 32; LDS = xt[32][68] + Ws[32][64] = 16.5KB.
// __launch_bounds__(256,8): VGPR<=64 -> 8 blocks/CU -> hist keeps ~2048 threads/CU.

__global__ __launch_bounds__(256, 8) void gemm_hist(const float* __restrict__ x,
                                                    const float* __restrict__ W,
                                                    unsigned* __restrict__ hb, int n,
                                                    const int* __restrict__ ei,
                                                    const float* __restrict__ ew,
                                                    unsigned long long* __restrict__ packed,
                                                    unsigned short* __restrict__ rank,
                                                    int E, int G, int T) {
    __shared__ float xt[32][68];   // padded: staging writes spread banks
    __shared__ float Ws[32][64];
    const int tid = threadIdx.x;
    const int bid = (int)blockIdx.x;

    const int g0 = (int)(((long long)bid * G) / T);
    const int g1 = (int)(((long long)(bid + 1) * G) / T);

    if (g1 == g0) {
        // ---- hist role ----
        int e = (bid - g0) * 256 + tid;
        if (e < E) {
            int c = ei[(long long)E + e];
            unsigned long long inc = (1ULL << 40) | (unsigned long long)(ew[e] * FIX_SCALE + 0.5f);
            unsigned long long old = atomicAdd(&packed[c], inc);
            rank[e] = (unsigned short)(old >> 40);
        }
        return;  // block-uniform exit before any __syncthreads
    }

    // ---- gemm role ----
    const int g = g0;
    const int brow = (g >> 1) * 64;
    const int chalf = g & 1;

    const int r0 = (tid >> 4) * 4;
    const int c0 = (tid & 15) * 4;
    float4 acc0 = make_float4(0, 0, 0, 0), acc1 = acc0, acc2 = acc0, acc3 = acc0;

    for (int kc = 0; kc < 4; kc++) {
        if (kc) __syncthreads();
        // stage x chunk transposed: 64 rows x 32 k = 512 float4
        #pragma unroll
        for (int ii = 0; ii < 2; ii++) {
            int i = tid + ii * 256;
            int r = i >> 3, c4 = i & 7, kl = c4 * 4;
            int gr = brow + r;
            float4 v = make_float4(0.f, 0.f, 0.f, 0.f);
            if (gr < n) v = *(const float4*)(x + (size_t)gr * 128 + kc * 32 + kl);
            xt[kl + 0][r] = v.x; xt[kl + 1][r] = v.y;
            xt[kl + 2][r] = v.z; xt[kl + 3][r] = v.w;
        }
        // stage W chunk: 32 k x 64 c = 512 float4
        #pragma unroll
        for (int ii = 0; ii < 2; ii++) {
            int i = tid + ii * 256;
            int k = i >> 4, c4 = i & 15;
            float4 v = *(const float4*)(W + (size_t)(kc * 32 + k) * 128 + chalf * 64 + c4 * 4);
            *(float4*)&Ws[k][c4 * 4] = v;
        }
        __syncthreads();

        #pragma unroll 8
        for (int k = 0; k < 32; k++) {
            float4 xa = *(const float4*)&xt[k][r0];
            float4 wb = *(const float4*)&Ws[k][c0];
            acc0.x += xa.x * wb.x; acc0.y += xa.x * wb.y; acc0.z += xa.x * wb.z; acc0.w += xa.x * wb.w;
            acc1.x += xa.y * wb.x; acc1.y += xa.y * wb.y; acc1.z += xa.y * wb.z; acc1.w += xa.y * wb.w;
            acc2.x += xa.z * wb.x; acc2.y += xa.z * wb.y; acc2.z += xa.z * wb.z; acc2.w += xa.z * wb.w;
            acc3.x += xa.w * wb.x; acc3.y += xa.w * wb.y; acc3.z += xa.w * wb.z; acc3.w += xa.w * wb.w;
        }
    }

    float4 accs[4] = {acc0, acc1, acc2, acc3};
    #pragma unroll
    for (int i = 0; i < 4; i++) {
        int gr = brow + r0 + i;
        if (gr < n) {
            uint2 p;
            p.x = pack_bf16x2(accs[i].x, accs[i].y);
            p.y = pack_bf16x2(accs[i].z, accs[i].w);
            *(uint2*)(hb + (size_t)gr * 64 + (chalf * 64 + c0) / 2) = p;
        }
    }
}

// plain hist (fallback path B, no rank)
__global__ __launch_bounds__(256) void hist_edges_plain(const int* __restrict__ ei,
                                                        const float* __restrict__ w,
                                                        unsigned long long* __restrict__ packed, int E) {
    int e = blockIdx.x * 256 + threadIdx.x;
    if (e >= E) return;
    int c = ei[(long long)E + e];
    unsigned long long inc = (1ULL << 40) | (unsigned long long)(w[e] * FIX_SCALE + 0.5f);
    atomicAdd(&packed[c], inc);
}

// standalone gemm (fallback path B)
__global__ __launch_bounds__(256) void gemm_xw(const float* __restrict__ x,
                                               const float* __restrict__ W,
                                               unsigned* __restrict__ hb, int n) {
    __shared__ float xt[128][64];
    __shared__ float Ws[128][64];
    const int tid = threadIdx.x;
    const int brow = blockIdx.x * 64;
    const int chalf = blockIdx.y;

    for (int i = tid; i < 64 * 32; i += 256) {
        int r = i >> 5, c4 = i & 31, k0 = c4 * 4;
        int gr = brow + r;
        float4 v = make_float4(0.f, 0.f, 0.f, 0.f);
        if (gr < n) v = *(const float4*)(x + (size_t)gr * 128 + k0);
        xt[k0 + 0][r] = v.x; xt[k0 + 1][r] = v.y;
        xt[k0 + 2][r] = v.z; xt[k0 + 3][r] = v.w;
    }
    for (int i = tid; i < 128 * 16; i += 256) {
        int k = i >> 4, c4 = i & 15;
        float4 v = *(const float4*)(W + (size_t)k * 128 + chalf * 64 + c4 * 4);
        *(float4*)&Ws[k][c4 * 4] = v;
    }
    __syncthreads();

    const int r0 = (tid >> 4) * 4;
    const int c0 = (tid & 15) * 4;
    float4 acc0 = make_float4(0, 0, 0, 0), acc1 = acc0, acc2 = acc0, acc3 = acc0;
    #pragma unroll 8
    for (int k = 0; k < 128; k++) {
        float4 xa = *(const float4*)&xt[k][r0];
        float4 wb = *(const float4*)&Ws[k][c0];
        acc0.x += xa.x * wb.x; acc0.y += xa.x * wb.y; acc0.z += xa.x * wb.z; acc0.w += xa.x * wb.w;
        acc1.x += xa.y * wb.x; acc1.y += xa.y * wb.y; acc1.z += xa.y * wb.z; acc1.w += xa.y * wb.w;
        acc2.x += xa.z * wb.x; acc2.y += xa.z * wb.y; acc2.z += xa.z * wb.z; acc2.w += xa.z * wb.w;
        acc3.x += xa.w * wb.x; acc3.y += xa.w * wb.y; acc3.z += xa.w * wb.z; acc3.w += xa.w * wb.w;
    }
    float4 accs[4] = {acc0, acc1, acc2, acc3};
    #pragma unroll
    for (int i = 0; i < 4; i++) {
        int gr = brow + r0 + i;
        if (gr < n) {
            uint2 p;
            p.x = pack_bf16x2(accs[i].x, accs[i].y);
            p.y = pack_bf16x2(accs[i].z, accs[i].w);
            *(uint2*)(hb + (size_t)gr * 64 + (chalf * 64 + c0) / 2) = p;
        }
    }
}

// ---------------- scan pass 1 (fused with dis = rsqrt(deg)) ----------------

__global__ __launch_bounds__(256) void scan_bsums_dis(const unsigned long long* __restrict__ packed,
                                                      int* __restrict__ bsum,
                                                      float* __restrict__ dis, int n) {
    int base = blockIdx.x * 1024;
    int t = threadIdx.x;
    int s = 0;
    #pragma unroll
    for (int k = 0; k < 4; k++) {
        int i = base + t * 4 + k;
        if (i < n) {
            unsigned long long p = packed[i];
            s += (int)(p >> 40);
            float d = (float)(p & MASK40) * FIX_INV;
            dis[i] = rsqrtf(fmaxf(d, 1e-30f));
        }
    }
    #pragma unroll
    for (int off = 32; off; off >>= 1) s += __shfl_xor(s, off);
    __shared__ int wsum[4];
    if ((t & 63) == 0) wsum[t >> 6] = s;
    __syncthreads();
    if (t == 0) bsum[blockIdx.x] = wsum[0] + wsum[1] + wsum[2] + wsum[3];
}

__global__ __launch_bounds__(256) void scan_boff(const int* __restrict__ bsum,
                                                 int* __restrict__ boff, int B,
                                                 int* __restrict__ rp, int n, int E) {
    int t = threadIdx.x;
    int v[4]; int loc = 0;
    #pragma unroll
    for (int k = 0; k < 4; k++) {
        int i = t * 4 + k;
        v[k] = (i < B) ? bsum[i] : 0;
        loc += v[k];
    }
    int lane = t & 63, wv = t >> 6;
    int incl = loc;
    #pragma unroll
    for (int off = 1; off < 64; off <<= 1) {
        int tt = __shfl_up(incl, off);
        if (lane >= off) incl += tt;
    }
    __shared__ int wsum[4];
    if (lane == 63) wsum[wv] = incl;
    __syncthreads();
    int woff = 0;
    for (int k = 0; k < wv; k++) woff += wsum[k];
    int run = woff + incl - loc;
    #pragma unroll
    for (int k = 0; k < 4; k++) {
        int i = t * 4 + k;
        if (i < B) boff[i] = run;
        run += v[k];
    }
    if (t == 0) rp[n] = E;
}

__global__ __launch_bounds__(256) void scan_write(const unsigned long long* __restrict__ packed,
                                                  const int* __restrict__ boff,
                                                  int* __restrict__ rp, int n) {
    int base = blockIdx.x * 1024;
    int t = threadIdx.x;
    int v[4]; int loc = 0;
    #pragma unroll
    for (int k = 0; k < 4; k++) {
        int i = base + t * 4 + k;
        v[k] = (i < n) ? (int)(packed[i] >> 40) : 0;
        loc += v[k];
    }
    int lane = t & 63, wv = t >> 6;
    int incl = loc;
    #pragma unroll
    for (int off = 1; off < 64; off <<= 1) {
        int tt = __shfl_up(incl, off);
        if (lane >= off) incl += tt;
    }
    __shared__ int wsum[4];
    if (lane == 63) wsum[wv] = incl;
    __syncthreads();
    int woff = 0;
    for (int k = 0; k < wv; k++) woff += wsum[k];
    int run = boff[blockIdx.x] + woff + incl - loc;
    #pragma unroll
    for (int k = 0; k < 4; k++) {
        int i = base + t * 4 + k;
        if (i < n) { rp[i] = run; run += v[k]; }
    }
}

// ---------------- counting-sort placement ----------------

__global__ __launch_bounds__(256) void sort_edges_rank(const int* __restrict__ ei,
                                                       const float* __restrict__ w,
                                                       const float* __restrict__ dis,
                                                       const int* __restrict__ rp,
                                                       const unsigned short* __restrict__ rank,
                                                       int2* __restrict__ es, int E) {
    int e = blockIdx.x * 256 + threadIdx.x;
    if (e >= E) return;
    int r = ei[e], c = ei[(long long)E + e];
    int pos = rp[c] + (int)rank[e];
    es[pos] = make_int2(r, __float_as_int(dis[r] * w[e]));
}

__global__ __launch_bounds__(256) void sort_edges_cursor(const int* __restrict__ ei,
                                                         const float* __restrict__ w,
                                                         const float* __restrict__ dis,
                                                         const int* __restrict__ rp,
                                                         int* __restrict__ cursor,
                                                         int2* __restrict__ es, int E) {
    int e = blockIdx.x * 256 + threadIdx.x;
    if (e >= E) return;
    int r = ei[e], c = ei[(long long)E + e];
    int pos = rp[c] + atomicAdd(&cursor[c], 1);
    es[pos] = make_int2(r, __float_as_int(dis[r] * w[e]));
}

// ---------------- CSR gather-aggregate + self-loop + bias + LN + ReLU ----------------
// one wave per node; lane l owns features 2l, 2l+1 (one bf16x2 uint per lane).

__global__ __launch_bounds__(256) void agg_ln(const int* __restrict__ rp,
                                              const int2* __restrict__ es,
                                              const unsigned* __restrict__ hb,
                                              const float* __restrict__ dis,
                                              const float* __restrict__ b,
                                              const float* __restrict__ gamma,
                                              const float* __restrict__ beta,
                                              float* __restrict__ out, int n) {
    const int wave = threadIdx.x >> 6;
    const int lane = threadIdx.x & 63;
    const int node = blockIdx.x * 4 + wave;
    if (node >= n) return;

    const int j0 = rp[node], j1 = rp[node + 1];
    const float ds = dis[node];

    float2 hs = unpack_bf16x2(hb[(size_t)node * 64 + lane]);
    float ax = ds * hs.x, ay = ds * hs.y;  // self-loop (coef = dis[i]*1)

    int j = j0;
    for (; j + 7 < j1; j += 8) {  // 8 outstanding gathers
        int2 ee[8]; unsigned uu[8];
        #pragma unroll
        for (int k = 0; k < 8; k++) ee[k] = es[j + k];
        #pragma unroll
        for (int k = 0; k < 8; k++) uu[k] = hb[(size_t)ee[k].x * 64 + lane];
        #pragma unroll
        for (int k = 0; k < 8; k++) {
            float c = __int_as_float(ee[k].y);
            float2 v = unpack_bf16x2(uu[k]);
            ax += c * v.x;
            ay += c * v.y;
        }
    }
    for (; j < j1; ++j) {
        int2 e0 = es[j];
        float2 v = unpack_bf16x2(hb[(size_t)e0.x * 64 + lane]);
        float c = __int_as_float(e0.y);
        ax += c * v.x;
        ay += c * v.y;
    }

    float2 bb = ((const float2*)b)[lane];
    float vx = ds * ax + bb.x;
    float vy = ds * ay + bb.y;

    float s = vx + vy;
    #pragma unroll
    for (int off = 32; off; off >>= 1) s += __shfl_xor(s, off);
    float mu = s * (1.0f / 128.0f);
    float dx = vx - mu, dy = vy - mu;
    float q = dx * dx + dy * dy;
    #pragma unroll
    for (int off = 32; off; off >>= 1) q += __shfl_xor(q, off);
    float rs = rsqrtf(q * (1.0f / 128.0f) + LN_EPS);

    float2 g = ((const float2*)gamma)[lane], be = ((const float2*)beta)[lane];
    float2 o;
    o.x = fmaxf(dx * rs * g.x + be.x, 0.f);
    o.y = fmaxf(dy * rs * g.y + be.y, 0.f);
    ((float2*)(out + (size_t)node * 128))[lane] = o;
}

// ---------------- launcher ----------------

extern "C" void kernel_launch(void* const* d_in, const int* in_sizes, int n_in,
                              void* d_out, int out_size, void* d_ws, size_t ws_size,
                              hipStream_t stream) {
    const float* x     = (const float*)d_in[0];
    const int*   ei    = (const int*)d_in[1];   // [2, E] int32
    const float* ew    = (const float*)d_in[2];
    const float* W     = (const float*)d_in[3];
    const float* b     = (const float*)d_in[4];
    const float* gamma = (const float*)d_in[5];
    const float* beta  = (const float*)d_in[6];

    const int n = in_sizes[0] / 128;
    const int E = in_sizes[2];
    float* out = (float*)d_out;

    char* ws = (char*)d_ws;
    const size_t MB = 1u << 20;

    unsigned long long* packed = (unsigned long long*)(ws);            // n*8
    float* dis  = (float*)(ws + 1 * MB);                               // n*4
    int*   rp   = (int*)(ws + 1 * MB + 512 * 1024);                    // (n+1)*4
    int*   bsum = (int*)(ws + 2 * MB);
    int*   boff = (int*)(ws + 2 * MB + 64 * 1024);

    const int B = (n + 1023) / 1024;

    // Path A (rank-based, atomic-free sort): rank @3MB, es @10MB, h(bf16) after es
    size_t esA_off = 10 * MB;
    size_t hA_off  = esA_off + (size_t)E * 8;
    size_t needA   = hA_off + (size_t)n * 128 * 2;
    // Path B (cursor atomics)
    size_t esB_off = 3 * MB;
    size_t hB_off  = esB_off + (size_t)E * 8;

    init_packed<<<(n + 255) / 256, 256, 0, stream>>>(packed, n);

    if (ws_size >= needA) {
        unsigned short* rank = (unsigned short*)(ws + 3 * MB);
        int2*     es = (int2*)(ws + esA_off);
        unsigned* hb = (unsigned*)(ws + hA_off);

        // fused hist (atomic stream) + gemm (compute), roles interleaved by blockIdx
        const int histBlocks = (E + 255) / 256;
        const int gemmBlocks = ((n + 63) / 64) * 2;
        const int T = histBlocks + gemmBlocks;
        gemm_hist<<<T, 256, 0, stream>>>(x, W, hb, n, ei, ew, packed, rank, E,
                                         gemmBlocks, T);

        scan_bsums_dis<<<B, 256, 0, stream>>>(packed, bsum, dis, n);
        scan_boff<<<1, 256, 0, stream>>>(bsum, boff, B, rp, n, E);
        scan_write<<<B, 256, 0, stream>>>(packed, boff, rp, n);
        sort_edges_rank<<<(E + 255) / 256, 256, 0, stream>>>(ei, ew, dis, rp, rank, es, E);

        agg_ln<<<(n + 3) / 4, 256, 0, stream>>>(rp, es, hb, dis, b, gamma, beta, out, n);
    } else {
        int*      cursor = (int*)(ws + 2 * MB + 256 * 1024);
        int2*     es = (int2*)(ws + esB_off);
        unsigned* hb = (unsigned*)(ws + hB_off);

        hipMemsetAsync(cursor, 0, (size_t)n * sizeof(int), stream);
        hist_edges_plain<<<(E + 255) / 256, 256, 0, stream>>>(ei, ew, packed, E);
        scan_bsums_dis<<<B, 256, 0, stream>>>(packed, bsum, dis, n);
        scan_boff<<<1, 256, 0, stream>>>(bsum, boff, B, rp, n, E);
        scan_write<<<B, 256, 0, stream>>>(packed, boff, rp, n);
        sort_edges_cursor<<<(E + 255) / 256, 256, 0, stream>>>(ei, ew, dis, rp, cursor, es, E);

        dim3 ggrid((n + 63) / 64, 2);
        gemm_xw<<<ggrid, 256, 0, stream>>>(x, W, hb, n);
        agg_ln<<<(n + 3) / 4, 256, 0, stream>>>(rp, es, hb, dis, b, gamma, beta, out, n);
    }
}

// Round 11
// 483.430 us; speedup vs baseline: 48.1317x; 1.0078x over previous
//
#include <hip/hip_runtime.h>

#define LN_EPS 1e-5f
#define FIX_SCALE 33554432.0f          // 2^25
#define FIX_INV   (1.0f / 33554432.0f)
#define MASK40    ((1ULL << 40) - 1)

// pack two f32 -> bf16x2 (round-to-nearest-even), lo in low 16 bits
__device__ __forceinline__ unsigned pack_bf16x2(float lo, float hi) {
    unsigned a = __float_as_uint(lo), b = __float_as_uint(hi);
    a = (a + 0x7FFFu + ((a >> 16) & 1u)) >> 16;
    b = (b + 0x7FFFu + ((b >> 16) & 1u)) >> 16;
    return a | (b << 16);
}

__device__ __forceinline__ float2 unpack_bf16x2(unsigned u) {
    return make_float2(__uint_as_float(u << 16), __uint_as_float(u & 0xFFFF0000u));
}

// ---------------- FUSED: hist (atomic, line-padded counters) + gemm ----------------
// packed[c * S]: count in bits[40:64), weight-sum (2^-25 fixed) in [0:40). Zero-initialized;
// self-loop +1.0 folded into dis computation. S = padding stride in u64 (16 -> one counter
// per 128B line) to break atomic line serialization.

__global__ __launch_bounds__(256, 8) void gemm_hist(const float* __restrict__ x,
                                                    const float* __restrict__ W,
                                                    unsigned* __restrict__ hb, int n,
                                                    const int* __restrict__ ei,
                                                    const float* __restrict__ ew,
                                                    unsigned long long* __restrict__ packed,
                                                    unsigned short* __restrict__ rank,
                                                    int E, int G, int T, int S) {
    __shared__ float xt[32][68];   // padded: staging writes spread banks
    __shared__ float Ws[32][64];
    const int tid = threadIdx.x;
    const int bid = (int)blockIdx.x;

    const int g0 = (int)(((long long)bid * G) / T);
    const int g1 = (int)(((long long)(bid + 1) * G) / T);

    if (g1 == g0) {
        // ---- hist role ----
        int e = (bid - g0) * 256 + tid;
        if (e < E) {
            int c = ei[(long long)E + e];
            unsigned long long inc = (1ULL << 40) | (unsigned long long)(ew[e] * FIX_SCALE + 0.5f);
            unsigned long long old = atomicAdd(&packed[(size_t)c * S], inc);
            rank[e] = (unsigned short)(old >> 40);
        }
        return;  // block-uniform exit before any __syncthreads
    }

    // ---- gemm role ----
    const int g = g0;
    const int brow = (g >> 1) * 64;
    const int chalf = g & 1;

    const int r0 = (tid >> 4) * 4;
    const int c0 = (tid & 15) * 4;
    float4 acc0 = make_float4(0, 0, 0, 0), acc1 = acc0, acc2 = acc0, acc3 = acc0;

    for (int kc = 0; kc < 4; kc++) {
        if (kc) __syncthreads();
        #pragma unroll
        for (int ii = 0; ii < 2; ii++) {
            int i = tid + ii * 256;
            int r = i >> 3, c4 = i & 7, kl = c4 * 4;
            int gr = brow + r;
            float4 v = make_float4(0.f, 0.f, 0.f, 0.f);
            if (gr < n) v = *(const float4*)(x + (size_t)gr * 128 + kc * 32 + kl);
            xt[kl + 0][r] = v.x; xt[kl + 1][r] = v.y;
            xt[kl + 2][r] = v.z; xt[kl + 3][r] = v.w;
        }
        #pragma unroll
        for (int ii = 0; ii < 2; ii++) {
            int i = tid + ii * 256;
            int k = i >> 4, c4 = i & 15;
            float4 v = *(const float4*)(W + (size_t)(kc * 32 + k) * 128 + chalf * 64 + c4 * 4);
            *(float4*)&Ws[k][c4 * 4] = v;
        }
        __syncthreads();

        #pragma unroll 8
        for (int k = 0; k < 32; k++) {
            float4 xa = *(const float4*)&xt[k][r0];
            float4 wb = *(const float4*)&Ws[k][c0];
            acc0.x += xa.x * wb.x; acc0.y += xa.x * wb.y; acc0.z += xa.x * wb.z; acc0.w += xa.x * wb.w;
            acc1.x += xa.y * wb.x; acc1.y += xa.y * wb.y; acc1.z += xa.y * wb.z; acc1.w += xa.y * wb.w;
            acc2.x += xa.z * wb.x; acc2.y += xa.z * wb.y; acc2.z += xa.z * wb.z; acc2.w += xa.z * wb.w;
            acc3.x += xa.w * wb.x; acc3.y += xa.w * wb.y; acc3.z += xa.w * wb.z; acc3.w += xa.w * wb.w;
        }
    }

    float4 accs[4] = {acc0, acc1, acc2, acc3};
    #pragma unroll
    for (int i = 0; i < 4; i++) {
        int gr = brow + r0 + i;
        if (gr < n) {
            uint2 p;
            p.x = pack_bf16x2(accs[i].x, accs[i].y);
            p.y = pack_bf16x2(accs[i].z, accs[i].w);
            *(uint2*)(hb + (size_t)gr * 64 + (chalf * 64 + c0) / 2) = p;
        }
    }
}

// ---------------- scan pass 1 (fused with dis = rsqrt(1 + wsum)) ----------------

__global__ __launch_bounds__(256) void scan_bsums_dis(const unsigned long long* __restrict__ packed,
                                                      int* __restrict__ bsum,
                                                      float* __restrict__ dis, int n, int S) {
    int base = blockIdx.x * 1024;
    int t = threadIdx.x;
    int s = 0;
    #pragma unroll
    for (int k = 0; k < 4; k++) {
        int i = base + t * 4 + k;
        if (i < n) {
            unsigned long long p = packed[(size_t)i * S];
            s += (int)(p >> 40);
            float d = 1.0f + (float)(p & MASK40) * FIX_INV;  // +1.0 = self-loop
            dis[i] = rsqrtf(d);
        }
    }
    #pragma unroll
    for (int off = 32; off; off >>= 1) s += __shfl_xor(s, off);
    __shared__ int wsum[4];
    if ((t & 63) == 0) wsum[t >> 6] = s;
    __syncthreads();
    if (t == 0) bsum[blockIdx.x] = wsum[0] + wsum[1] + wsum[2] + wsum[3];
}

__global__ __launch_bounds__(256) void scan_boff(const int* __restrict__ bsum,
                                                 int* __restrict__ boff, int B,
                                                 int* __restrict__ rp, int n, int E) {
    int t = threadIdx.x;
    int v[4]; int loc = 0;
    #pragma unroll
    for (int k = 0; k < 4; k++) {
        int i = t * 4 + k;
        v[k] = (i < B) ? bsum[i] : 0;
        loc += v[k];
    }
    int lane = t & 63, wv = t >> 6;
    int incl = loc;
    #pragma unroll
    for (int off = 1; off < 64; off <<= 1) {
        int tt = __shfl_up(incl, off);
        if (lane >= off) incl += tt;
    }
    __shared__ int wsum[4];
    if (lane == 63) wsum[wv] = incl;
    __syncthreads();
    int woff = 0;
    for (int k = 0; k < wv; k++) woff += wsum[k];
    int run = woff + incl - loc;
    #pragma unroll
    for (int k = 0; k < 4; k++) {
        int i = t * 4 + k;
        if (i < B) boff[i] = run;
        run += v[k];
    }
    if (t == 0) rp[n] = E;
}

__global__ __launch_bounds__(256) void scan_write(const unsigned long long* __restrict__ packed,
                                                  const int* __restrict__ boff,
                                                  int* __restrict__ rp, int n, int S) {
    int base = blockIdx.x * 1024;
    int t = threadIdx.x;
    int v[4]; int loc = 0;
    #pragma unroll
    for (int k = 0; k < 4; k++) {
        int i = base + t * 4 + k;
        v[k] = (i < n) ? (int)(packed[(size_t)i * S] >> 40) : 0;
        loc += v[k];
    }
    int lane = t & 63, wv = t >> 6;
    int incl = loc;
    #pragma unroll
    for (int off = 1; off < 64; off <<= 1) {
        int tt = __shfl_up(incl, off);
        if (lane >= off) incl += tt;
    }
    __shared__ int wsum[4];
    if (lane == 63) wsum[wv] = incl;
    __syncthreads();
    int woff = 0;
    for (int k = 0; k < wv; k++) woff += wsum[k];
    int run = boff[blockIdx.x] + woff + incl - loc;
    #pragma unroll
    for (int k = 0; k < 4; k++) {
        int i = base + t * 4 + k;
        if (i < n) { rp[i] = run; run += v[k]; }
    }
}

// ---------------- counting-sort placement (atomic-free via rank) ----------------

__global__ __launch_bounds__(256) void sort_edges_rank(const int* __restrict__ ei,
                                                       const float* __restrict__ w,
                                                       const float* __restrict__ dis,
                                                       const int* __restrict__ rp,
                                                       const unsigned short* __restrict__ rank,
                                                       int2* __restrict__ es, int E) {
    int e = blockIdx.x * 256 + threadIdx.x;
    if (e >= E) return;
    int r = ei[e], c = ei[(long long)E + e];
    int pos = rp[c] + (int)rank[e];
    es[pos] = make_int2(r, __float_as_int(dis[r] * w[e]));
}

// ---------------- CSR gather-aggregate + self-loop + bias + LN + ReLU ----------------
// one wave per node; lane l owns features 2l, 2l+1 (one bf16x2 uint per lane).

__global__ __launch_bounds__(256) void agg_ln(const int* __restrict__ rp,
                                              const int2* __restrict__ es,
                                              const unsigned* __restrict__ hb,
                                              const float* __restrict__ dis,
                                              const float* __restrict__ b,
                                              const float* __restrict__ gamma,
                                              const float* __restrict__ beta,
                                              float* __restrict__ out, int n) {
    const int wave = threadIdx.x >> 6;
    const int lane = threadIdx.x & 63;
    const int node = blockIdx.x * 4 + wave;
    if (node >= n) return;

    const int j0 = rp[node], j1 = rp[node + 1];
    const float ds = dis[node];

    float2 hs = unpack_bf16x2(hb[(size_t)node * 64 + lane]);
    float ax = ds * hs.x, ay = ds * hs.y;  // self-loop (coef = dis[i]*1)

    int j = j0;
    for (; j + 7 < j1; j += 8) {  // 8 outstanding gathers
        int2 ee[8]; unsigned uu[8];
        #pragma unroll
        for (int k = 0; k < 8; k++) ee[k] = es[j + k];
        #pragma unroll
        for (int k = 0; k < 8; k++) uu[k] = hb[(size_t)ee[k].x * 64 + lane];
        #pragma unroll
        for (int k = 0; k < 8; k++) {
            float c = __int_as_float(ee[k].y);
            float2 v = unpack_bf16x2(uu[k]);
            ax += c * v.x;
            ay += c * v.y;
        }
    }
    for (; j < j1; ++j) {
        int2 e0 = es[j];
        float2 v = unpack_bf16x2(hb[(size_t)e0.x * 64 + lane]);
        float c = __int_as_float(e0.y);
        ax += c * v.x;
        ay += c * v.y;
    }

    float2 bb = ((const float2*)b)[lane];
    float vx = ds * ax + bb.x;
    float vy = ds * ay + bb.y;

    float s = vx + vy;
    #pragma unroll
    for (int off = 32; off; off >>= 1) s += __shfl_xor(s, off);
    float mu = s * (1.0f / 128.0f);
    float dx = vx - mu, dy = vy - mu;
    float q = dx * dx + dy * dy;
    #pragma unroll
    for (int off = 32; off; off >>= 1) q += __shfl_xor(q, off);
    float rs = rsqrtf(q * (1.0f / 128.0f) + LN_EPS);

    float2 g = ((const float2*)gamma)[lane], be = ((const float2*)beta)[lane];
    float2 o;
    o.x = fmaxf(dx * rs * g.x + be.x, 0.f);
    o.y = fmaxf(dy * rs * g.y + be.y, 0.f);
    ((float2*)(out + (size_t)node * 128))[lane] = o;
}

// ---------------- launcher ----------------

static inline size_t align256(size_t o) { return (o + 255) & ~(size_t)255; }

extern "C" void kernel_launch(void* const* d_in, const int* in_sizes, int n_in,
                              void* d_out, int out_size, void* d_ws, size_t ws_size,
                              hipStream_t stream) {
    const float* x     = (const float*)d_in[0];
    const int*   ei    = (const int*)d_in[1];   // [2, E] int32
    const float* ew    = (const float*)d_in[2];
    const float* W     = (const float*)d_in[3];
    const float* b     = (const float*)d_in[4];
    const float* gamma = (const float*)d_in[5];
    const float* beta  = (const float*)d_in[6];

    const int n = in_sizes[0] / 128;
    const int E = in_sizes[2];
    float* out = (float*)d_out;
    char* ws = (char*)d_ws;

    // total ws needed for padding stride S (u64 units)
    auto need = [&](size_t S) -> size_t {
        size_t o = 0;
        o = align256(o + (size_t)n * S * 8);   // packed counters
        o = align256(o + (size_t)n * 4);       // dis
        o = align256(o + (size_t)(n + 1) * 4); // rp
        o = align256(o + 4096);                // bsum
        o = align256(o + 4096);                // boff
        o = align256(o + (size_t)E * 2);       // rank
        o = align256(o + (size_t)E * 8);       // es
        o = align256(o + (size_t)n * 256);     // hb (bf16 h)
        return o;
    };
    const int S = (ws_size >= need(16)) ? 16 : ((ws_size >= need(2)) ? 2 : 1);

    size_t o = 0;
    unsigned long long* packed = (unsigned long long*)(ws + o); o = align256(o + (size_t)n * S * 8);
    float*          dis  = (float*)(ws + o);          o = align256(o + (size_t)n * 4);
    int*            rp   = (int*)(ws + o);            o = align256(o + (size_t)(n + 1) * 4);
    int*            bsum = (int*)(ws + o);            o = align256(o + 4096);
    int*            boff = (int*)(ws + o);            o = align256(o + 4096);
    unsigned short* rank = (unsigned short*)(ws + o); o = align256(o + (size_t)E * 2);
    int2*           es   = (int2*)(ws + o);           o = align256(o + (size_t)E * 8);
    unsigned*       hb   = (unsigned*)(ws + o);

    hipMemsetAsync(packed, 0, (size_t)n * S * 8, stream);

    const int histBlocks = (E + 255) / 256;
    const int gemmBlocks = ((n + 63) / 64) * 2;
    const int T = histBlocks + gemmBlocks;
    gemm_hist<<<T, 256, 0, stream>>>(x, W, hb, n, ei, ew, packed, rank, E,
                                     gemmBlocks, T, S);

    const int B = (n + 1023) / 1024;
    scan_bsums_dis<<<B, 256, 0, stream>>>(packed, bsum, dis, n, S);
    scan_boff<<<1, 256, 0, stream>>>(bsum, boff, B, rp, n, E);
    scan_write<<<B, 256, 0, stream>>>(packed, boff, rp, n, S);
    sort_edges_rank<<<(E + 255) / 256, 256, 0, stream>>>(ei, ew, dis, rp, rank, es, E);

    agg_ln<<<(n + 3) / 4, 256, 0, stream>>>(rp, es, hb, dis, b, gamma, beta, out, n);
}